// Round 7
// baseline (543.271 us; speedup 1.0000x reference)
//
#include <hip/hip_runtime.h>
#include <math.h>

// ---------------------------------------------------------------------------
// GCN: 3x (GEMM(+dis scale, bf16 blocked out) -> 4-pass pull-aggregate)
//      -> mean pool -> head -> log_softmax
// R7: gather table blocked into 4 feature slices of 32 feats (3.2 MB each,
//     [pass][N][32] bf16) so each pass's slice is L2-resident per XCD
//     (R5/R6 pinned at 3.2 TB/s: 12.8 MB table forced 8x XCD replication +
//     capacity misses). Pass-major blockIdx ordering keeps resident blocks
//     on the same slice. Quarter-wave gathers (16 lanes x 64 B row),
//     per-node aligned LDS index regions, ushort4 index loads, dbuf gathers.
// ---------------------------------------------------------------------------

#define BLK_EDGES 4096
#define MAXB 128          // max dst-buckets for CSR build (N<=65536)

static __device__ inline unsigned short f2bf(float f) {
    unsigned u = __float_as_uint(f);
    unsigned r = (u + 0x7FFFu + ((u >> 16) & 1u)) >> 16;   // RNE
    return (unsigned short)r;
}
static __device__ inline float bf_lo(unsigned u) { return __uint_as_float(u << 16); }
static __device__ inline float bf_hi(unsigned u) { return __uint_as_float(u & 0xFFFF0000u); }

// ---- per-block bucket histogram (bucket = dst >> 9), transposed output ----
__global__ __launch_bounds__(256) void blk_hist(const int* __restrict__ dst,
        int* __restrict__ histT, int E, int NBLK, int NB) {
    __shared__ int h[MAXB];
    int blk = blockIdx.x, t = threadIdx.x;
    for (int i = t; i < NB; i += 256) h[i] = 0;
    __syncthreads();
    int lo = blk * BLK_EDGES;
    int hi = min(E, lo + BLK_EDGES);
    for (int i = lo + t; i < hi; i += 256)
        atomicAdd(&h[dst[i] >> 9], 1);
    __syncthreads();
    for (int i = t; i < NB; i += 256) histT[i * NBLK + blk] = h[i];
}

// ---- 3-kernel exclusive scan (n <= 65536) ---------------------------------
__global__ void scan_block(const int* __restrict__ cnt, int* __restrict__ off,
                           int* __restrict__ bsum, int n) {
    __shared__ int lds[256];
    int t = threadIdx.x;
    int i = blockIdx.x * 256 + t;
    int v = (i < n) ? cnt[i] : 0;
    lds[t] = v;
    __syncthreads();
    for (int d = 1; d < 256; d <<= 1) {
        int add = (t >= d) ? lds[t - d] : 0;
        __syncthreads();
        lds[t] += add;
        __syncthreads();
    }
    if (i < n) off[i] = lds[t] - v;
    if (t == 255) bsum[blockIdx.x] = lds[255];
}

__global__ void scan_top(const int* __restrict__ bsum, int* __restrict__ boff,
                         int* __restrict__ off, int nblocks, int n) {
    __shared__ int lds[256];
    int t = threadIdx.x;
    int v = (t < nblocks) ? bsum[t] : 0;
    lds[t] = v;
    __syncthreads();
    for (int d = 1; d < 256; d <<= 1) {
        int add = (t >= d) ? lds[t - d] : 0;
        __syncthreads();
        lds[t] += add;
        __syncthreads();
    }
    if (t < nblocks) boff[t] = lds[t] - v;
    if (t == 255) off[n] = lds[255];
}

__global__ void scan_add(int* __restrict__ off, const int* __restrict__ boff, int n) {
    int i = blockIdx.x * 256 + threadIdx.x;
    if (i < n) off[i] += boff[blockIdx.x];
}

// ---- scatter packed edges into private (block,bucket) runs ----------------
__global__ __launch_bounds__(256) void scatter_packed(const int* __restrict__ src,
        const int* __restrict__ dst, const int* __restrict__ P,
        unsigned* __restrict__ packed, int E, int NBLK, int NB) {
    __shared__ int cur[MAXB];
    int blk = blockIdx.x, t = threadIdx.x;
    for (int i = t; i < NB; i += 256) cur[i] = P[i * NBLK + blk];
    __syncthreads();
    int lo = blk * BLK_EDGES;
    int hi = min(E, lo + BLK_EDGES);
    for (int i = lo + t; i < hi; i += 256) {
        int d = dst[i];
        int pos = atomicAdd(&cur[d >> 9], 1);   // LDS atomic, block-local
        packed[pos] = ((unsigned)d << 16) | (unsigned)src[i];
    }
}

// ---- per-bucket: node counts, local scan -> off/dis, fill ushort CSR ------
__global__ __launch_bounds__(256) void bucket_build(const unsigned* __restrict__ packed,
        const int* __restrict__ P, int* __restrict__ off, float* __restrict__ dis,
        unsigned short* __restrict__ csr16, int E, int NBLK, int N, int NB) {
    __shared__ int cnt[512];
    __shared__ int loc[512];
    __shared__ int ps[256];
    int b = blockIdx.x, t = threadIdx.x;
    int start = P[b * NBLK];
    int end   = P[(b + 1) * NBLK];
    cnt[t] = 0; cnt[t + 256] = 0;
    __syncthreads();
    for (int i = start + t; i < end; i += 256)
        atomicAdd(&cnt[(packed[i] >> 16) & 511], 1);
    __syncthreads();
    int c0 = cnt[2 * t], c1 = cnt[2 * t + 1];
    ps[t] = c0 + c1;
    __syncthreads();
    for (int d = 1; d < 256; d <<= 1) {
        int add = (t >= d) ? ps[t - d] : 0;
        __syncthreads();
        ps[t] += add;
        __syncthreads();
    }
    int pexcl = ps[t] - (c0 + c1);
    loc[2 * t]     = start + pexcl;
    loc[2 * t + 1] = start + pexcl + c0;
    __syncthreads();
    int node0 = b * 512;
    for (int l = t; l < 512; l += 256) {
        int node = node0 + l;
        if (node < N) {
            off[node] = loc[l];
            dis[node] = rsqrtf((float)cnt[l] + 1.0f);
        }
    }
    if (b == NB - 1 && t == 0) off[N] = E;
    __syncthreads();
    for (int i = start + t; i < end; i += 256) {
        unsigned p = packed[i];
        int l = (p >> 16) & 511;
        int pos = atomicAdd(&loc[l], 1);
        csr16[pos] = (unsigned short)(p & 0xFFFFu);
    }
}

// ---- GEMM: Hs16 (blocked [4][n][32] bf16) = dis[r] * (A[r] @ W) -----------
// A: fp32 flat [n][128] (layer 0) or bf16 blocked [4][n][32] (layers 1/2).
template<int IN_BF16>
__global__ __launch_bounds__(256, 2) void gemm128v4(const void* __restrict__ Av,
        const float* __restrict__ W, const float* __restrict__ dis,
        unsigned short* __restrict__ Hs16, int n) {
    __shared__ float As[64 * 128];   // As[k*128 + r]
    __shared__ float Ws[64 * 128];   // Ws[k*128 + c]
    int t = threadIdx.x;
    int row0 = blockIdx.x * 128;
    int rg = (t & 15) * 8;
    int cg = (t >> 4) * 8;

    float acc[8][8];
#pragma unroll
    for (int i = 0; i < 8; ++i)
#pragma unroll
        for (int j = 0; j < 8; ++j) acc[i][j] = 0.f;

    for (int kk = 0; kk < 128; kk += 64) {
        __syncthreads();
        {
            int r = t & 127;
            int q = t >> 7;          // covers k range [kk+q*32, kk+q*32+32)
            int grow = row0 + r;
            if (IN_BF16) {
                // slice index p equals the 32-wide k-chunk index
                int p = (kk >> 5) + q;
                const unsigned short* Ap = (const unsigned short*)Av
                                           + ((size_t)p * n + grow) * 32;
#pragma unroll
                for (int j = 0; j < 4; ++j) {
                    uint4 u;
                    if (grow < n) u = ((const uint4*)Ap)[j];
                    else          u = uint4{0u, 0u, 0u, 0u};
                    int kb = q * 32 + j * 8;
                    As[(kb + 0) * 128 + r] = bf_lo(u.x);
                    As[(kb + 1) * 128 + r] = bf_hi(u.x);
                    As[(kb + 2) * 128 + r] = bf_lo(u.y);
                    As[(kb + 3) * 128 + r] = bf_hi(u.y);
                    As[(kb + 4) * 128 + r] = bf_lo(u.z);
                    As[(kb + 5) * 128 + r] = bf_hi(u.z);
                    As[(kb + 6) * 128 + r] = bf_lo(u.w);
                    As[(kb + 7) * 128 + r] = bf_hi(u.w);
                }
            } else {
                const float* Ap = (const float*)Av + (size_t)grow * 128 + kk + q * 32;
#pragma unroll
                for (int j = 0; j < 8; ++j) {
                    float4 f;
                    if (grow < n) f = ((const float4*)Ap)[j];
                    else          f = float4{0.f, 0.f, 0.f, 0.f};
                    int kb = q * 32 + j * 4;
                    As[(kb + 0) * 128 + r] = f.x;
                    As[(kb + 1) * 128 + r] = f.y;
                    As[(kb + 2) * 128 + r] = f.z;
                    As[(kb + 3) * 128 + r] = f.w;
                }
            }
        }
        {
            const float4* Wp = (const float4*)(W + (size_t)kk * 128);
            float4* Wl = (float4*)Ws;
            for (int i = t; i < 64 * 128 / 4; i += 256) Wl[i] = Wp[i];
        }
        __syncthreads();
#pragma unroll 4
        for (int k = 0; k < 64; ++k) {
            float4 a0 = *(const float4*)&As[k * 128 + rg];
            float4 a1 = *(const float4*)&As[k * 128 + rg + 4];
            float4 w0 = *(const float4*)&Ws[k * 128 + cg];
            float4 w1 = *(const float4*)&Ws[k * 128 + cg + 4];
            float a[8] = {a0.x, a0.y, a0.z, a0.w, a1.x, a1.y, a1.z, a1.w};
            float w[8] = {w0.x, w0.y, w0.z, w0.w, w1.x, w1.y, w1.z, w1.w};
#pragma unroll
            for (int i = 0; i < 8; ++i)
#pragma unroll
                for (int j = 0; j < 8; ++j)
                    acc[i][j] = fmaf(a[i], w[j], acc[i][j]);
        }
    }
    // epilogue: scale by dis[row], write bf16 into blocked slice layout
    int po = cg >> 5;          // output slice
    int c0 = cg & 31;          // col within slice
#pragma unroll
    for (int i = 0; i < 8; ++i) {
        int r = row0 + rg + i;
        if (r < n) {
            float d = dis[r];
            unsigned u0 = (unsigned)f2bf(acc[i][0] * d) | ((unsigned)f2bf(acc[i][1] * d) << 16);
            unsigned u1 = (unsigned)f2bf(acc[i][2] * d) | ((unsigned)f2bf(acc[i][3] * d) << 16);
            unsigned u2 = (unsigned)f2bf(acc[i][4] * d) | ((unsigned)f2bf(acc[i][5] * d) << 16);
            unsigned u3 = (unsigned)f2bf(acc[i][6] * d) | ((unsigned)f2bf(acc[i][7] * d) << 16);
            uint4 o = {u0, u1, u2, u3};
            *(uint4*)(Hs16 + ((size_t)po * n + r) * 32 + c0) = o;
        }
    }
}

// ---- 4-pass pull aggregation over blocked bf16 table ----------------------
// grid = 4 * nb4 blocks, pass-major (pass = bid / nb4) so concurrently
// resident blocks share one 3.2 MB L2-resident slice. One wave per node,
// quarter-wave per edge (16 lanes x 4 B = 64 B row slice), per-node aligned
// LDS index regions, ushort4 index loads, double-buffered gathers.
template<int DO_TANH, int OUT_BF16>
__global__ __launch_bounds__(256) void aggregate4(const unsigned short* __restrict__ hs,
    const unsigned short* __restrict__ csr, const int* __restrict__ off,
    const float* __restrict__ dis, const float* __restrict__ bias,
    void* __restrict__ outp, int n, int nb4) {
    __shared__ unsigned short eidx[4][512];
    int t = threadIdx.x;
    int bid = blockIdx.x;
    int pass = bid / nb4;
    int nblk = bid - pass * nb4;
    int w = t >> 6;
    int node = nblk * 4 + w;
    if (node >= n) return;            // whole wave exits; no barriers used
    int lane = t & 63;
    int q = lane >> 4;                // edge quarter 0..3
    int fq = lane & 15;               // covers feats [pass*32 + 2*fq, +2)
    const unsigned* H = (const unsigned*)hs + (size_t)pass * n * 16;

    int e0 = off[node];
    int m = off[node + 1] - e0;
    float ax = 0.f, ay = 0.f;

    if (m <= 512) {
        // wave-private staging (same-wave DS ops are ordered; no barrier)
        for (int i = lane; i < m; i += 64) eidx[w][i] = csr[e0 + i];
        int nfull = m & ~15;
        unsigned va[4], vb[4];
        auto load = [&](int i, unsigned* v) {
            ushort4 sq = *(const ushort4*)&eidx[w][i + q * 4];
            v[0] = H[(size_t)sq.x * 16 + fq];
            v[1] = H[(size_t)sq.y * 16 + fq];
            v[2] = H[(size_t)sq.z * 16 + fq];
            v[3] = H[(size_t)sq.w * 16 + fq];
        };
        auto sum = [&](unsigned* v) {
#pragma unroll
            for (int j = 0; j < 4; ++j) {
                ax += bf_lo(v[j]);
                ay += bf_hi(v[j]);
            }
        };
        int B = nfull >> 4;
        if (B) {
            load(0, va);
            int k = 1;
            for (; k + 1 < B; k += 2) {
                load(k << 4, vb);       sum(va);
                load((k + 1) << 4, va); sum(vb);
            }
            if (k < B) { load(k << 4, vb); sum(va); sum(vb); }
            else       { sum(va); }
        }
        for (int e = nfull + q; e < m; e += 4) {
            unsigned s = eidx[w][e];
            unsigned v = H[(size_t)s * 16 + fq];
            ax += bf_lo(v);
            ay += bf_hi(v);
        }
    } else {
        // rare fallback: degree > 512
        for (int e = q; e < m; e += 4) {
            unsigned s = csr[e0 + e];
            unsigned v = H[(size_t)s * 16 + fq];
            ax += bf_lo(v);
            ay += bf_hi(v);
        }
    }
    // reduce across the 4 edge quarters (lanes sharing fq)
    ax += __shfl_xor(ax, 16, 64);
    ax += __shfl_xor(ax, 32, 64);
    ay += __shfl_xor(ay, 16, 64);
    ay += __shfl_xor(ay, 32, 64);

    unsigned sv = H[(size_t)node * 16 + fq];   // self loop (pre-scaled by dn)
    ax += bf_lo(sv);
    ay += bf_hi(sv);

    float dn = dis[node];
    float2 bv = *(const float2*)(bias + pass * 32 + fq * 2);
    float ox = fmaf(dn, ax, bv.x);
    float oy = fmaf(dn, ay, bv.y);
    if (DO_TANH) { ox = tanhf(ox); oy = tanhf(oy); }
    if (q == 0) {
        if (OUT_BF16) {
            unsigned o = (unsigned)f2bf(ox) | ((unsigned)f2bf(oy) << 16);
            ((unsigned*)outp)[((size_t)pass * n + node) * 16 + fq] = o;
        } else {
            float2 o = {ox, oy};
            *(float2*)((float*)outp + ((size_t)pass * n + node) * 32 + fq * 2) = o;
        }
    }
}

// ---- per-graph node ranges via binary search on sorted batch --------------
__global__ void graph_starts(const int* __restrict__ batch, int* __restrict__ gstart,
                             int n, int G) {
    int g = blockIdx.x * 64 + threadIdx.x;
    if (g > G) return;
    int lo = 0, hi = n;
    while (lo < hi) {
        int mid = (lo + hi) >> 1;
        if (batch[mid] < g) lo = mid + 1; else hi = mid;
    }
    gstart[g] = lo;
}

// ---- mean pool over blocked fp32 act [4][N][32] ---------------------------
__global__ __launch_bounds__(64) void pool_mean(const float* __restrict__ actf,
    const int* __restrict__ gstart, float* __restrict__ pooled, int G, int N) {
    int g = blockIdx.x;
    int l = threadIdx.x;
    int p = l >> 4;
    int c = (l & 15) * 2;
    const float* base = actf + (size_t)p * N * 32 + c;
    int lo = gstart[g], hi = gstart[g + 1];
    float ax = 0.f, ay = 0.f;
    for (int i = lo; i < hi; ++i) {
        const float2 v = *(const float2*)(base + (size_t)i * 32);
        ax += v.x;
        ay += v.y;
    }
    int cnt = hi - lo;
    float inv = 1.0f / (float)(cnt > 0 ? cnt : 1);
    pooled[(size_t)g * 128 + p * 32 + c]     = ax * inv;
    pooled[(size_t)g * 128 + p * 32 + c + 1] = ay * inv;
}

__global__ __launch_bounds__(64) void head_kernel(const float* __restrict__ pooled,
    const float* __restrict__ Wout, const float* __restrict__ bout,
    float* __restrict__ out, int C) {
    __shared__ float l[16];
    __shared__ float stats[2];
    int g = blockIdx.x;
    int t = threadIdx.x;
    if (t < C) {
        float acc = bout[t];
        for (int f = 0; f < 128; ++f)
            acc = fmaf(pooled[(size_t)g * 128 + f], Wout[(size_t)f * C + t], acc);
        l[t] = acc;
    }
    __syncthreads();
    if (t == 0) {
        float m = -1e30f;
        for (int c = 0; c < C; ++c) m = fmaxf(m, l[c]);
        float s = 0.f;
        for (int c = 0; c < C; ++c) s += expf(l[c] - m);
        stats[0] = m;
        stats[1] = logf(s);
    }
    __syncthreads();
    if (t < C) out[(size_t)g * C + t] = l[t] - stats[0] - stats[1];
}

// ---------------------------------------------------------------------------
extern "C" void kernel_launch(void* const* d_in, const int* in_sizes, int n_in,
                              void* d_out, int out_size, void* d_ws, size_t ws_size,
                              hipStream_t stream) {
    const float* x     = (const float*)d_in[0];
    const int*   edge  = (const int*)d_in[1];
    const int*   batch = (const int*)d_in[2];
    const float* W0 = (const float*)d_in[3];
    const float* b0 = (const float*)d_in[4];
    const float* W1 = (const float*)d_in[5];
    const float* b1 = (const float*)d_in[6];
    const float* W2 = (const float*)d_in[7];
    const float* b2 = (const float*)d_in[8];
    const float* Wout = (const float*)d_in[9];
    const float* bout = (const float*)d_in[10];
    float* out = (float*)d_out;

    const int N = in_sizes[0] / 128;   // 50000 (< 65536 required for packing)
    const int E = in_sizes[1] / 2;     // 1600000
    const int C = in_sizes[10];        // 10
    const int G = out_size / C;        // 512

    const int* src = edge;
    const int* dst = edge + E;

    const int NBLK = (E + BLK_EDGES - 1) / BLK_EDGES;  // 391
    const int NB   = (N + 511) / 512;                  // 98 buckets
    const int NBQ  = NB * NBLK;                        // 38318 scan entries

    char* p = (char*)d_ws;
    auto alloc = [&](size_t bytes) -> void* {
        void* r = (void*)p;
        p += (bytes + 255) & ~(size_t)255;
        return r;
    };
    unsigned short* hs = (unsigned short*)alloc((size_t)N * 128 * 2);  // blocked bf16
    float* act    = (float*)alloc((size_t)N * 128 * 4);  // blocked bf16 or fp32
    float* dis    = (float*)alloc((size_t)N * 4);
    int*   off    = (int*)alloc((size_t)(N + 1) * 4);
    int*   P      = (int*)alloc((size_t)(NBQ + 1) * 4);
    int*   bsum   = (int*)alloc(256 * 4);
    int*   boff   = (int*)alloc(256 * 4);
    unsigned* packed = (unsigned*)alloc((size_t)E * 4);
    unsigned short* csr16 = (unsigned short*)alloc((size_t)E * 2);
    int*   gstart  = (int*)alloc((size_t)(G + 1) * 4);
    float* pooled  = (float*)alloc((size_t)G * 128 * 4);

    const int sb = (NBQ + 255) / 256;   // 150 (<=256 required by scan_top)

    // CSR build (no contended global atomics anywhere)
    blk_hist<<<NBLK, 256, 0, stream>>>(dst, P, E, NBLK, NB);
    scan_block<<<sb, 256, 0, stream>>>(P, P, bsum, NBQ);
    scan_top<<<1, 256, 0, stream>>>(bsum, boff, P, sb, NBQ);
    scan_add<<<sb, 256, 0, stream>>>(P, boff, NBQ);
    scatter_packed<<<NBLK, 256, 0, stream>>>(src, dst, P, packed, E, NBLK, NB);
    bucket_build<<<NB, 256, 0, stream>>>(packed, P, off, dis, csr16, E, NBLK, N, NB);

    const int gb  = (N + 127) / 128;
    const int nb4 = (N + 3) / 4;

    gemm128v4<0><<<gb, 256, 0, stream>>>(x,   W0, dis, hs, N);
    aggregate4<1, 1><<<4 * nb4, 256, 0, stream>>>(hs, csr16, off, dis, b0, act, N, nb4);
    gemm128v4<1><<<gb, 256, 0, stream>>>(act, W1, dis, hs, N);
    aggregate4<1, 1><<<4 * nb4, 256, 0, stream>>>(hs, csr16, off, dis, b1, act, N, nb4);
    gemm128v4<1><<<gb, 256, 0, stream>>>(act, W2, dis, hs, N);
    aggregate4<0, 0><<<4 * nb4, 256, 0, stream>>>(hs, csr16, off, dis, b2, act, N, nb4);

    graph_starts<<<(G + 64) / 64, 64, 0, stream>>>(batch, gstart, N, G);
    pool_mean<<<G, 64, 0, stream>>>(act, gstart, pooled, G, N);
    head_kernel<<<G, 64, 0, stream>>>(pooled, Wout, bout, out, C);
}

// Round 10
// 423.405 us; speedup vs baseline: 1.2831x; 1.2831x over previous
//
#include <hip/hip_runtime.h>
#include <math.h>

// ---------------------------------------------------------------------------
// GCN: 3x (MFMA GEMM(+dis scale, bf16) -> pull-aggregate -> bias -> tanh)
//      -> mean pool -> head -> log_softmax
// R10: R9 with the real bug fixed — W^T LDS staging covered only k=0..63
//      (j=i&7 -> 8 of 16 uint4 chunks/row); k=64..127 was uninitialized LDS,
//      which is what produced R8's NaN and R9's clamp-value output. Loop now
//      stages all 16 chunks. Layouts unchanged; sanitizer retained.
// ---------------------------------------------------------------------------

#define BLK_EDGES 4096
#define MAXB 128          // max dst-buckets for CSR build (N<=65536)
#define ECAP 2048         // LDS edge-index capacity per aggregate block
#define WS_STRIDE 136     // LDS row stride for W^T (elements; 272B, 16B-aligned)

typedef __attribute__((ext_vector_type(8))) short bf16x8;
typedef __attribute__((ext_vector_type(4))) float f32x4;

static __device__ inline unsigned short f2bf(float f) {
    unsigned u = __float_as_uint(f);
    unsigned r = (u + 0x7FFFu + ((u >> 16) & 1u)) >> 16;   // RNE
    return (unsigned short)r;
}
static __device__ inline float bf_lo(unsigned u) { return __uint_as_float(u << 16); }
static __device__ inline float bf_hi(unsigned u) { return __uint_as_float(u & 0xFFFF0000u); }

// ---- per-block bucket histogram (bucket = dst >> 9), transposed output ----
__global__ __launch_bounds__(256) void blk_hist(const int* __restrict__ dst,
        int* __restrict__ histT, int E, int NBLK, int NB) {
    __shared__ int h[MAXB];
    int blk = blockIdx.x, t = threadIdx.x;
    for (int i = t; i < NB; i += 256) h[i] = 0;
    __syncthreads();
    int lo = blk * BLK_EDGES;
    int hi = min(E, lo + BLK_EDGES);
    for (int i = lo + t; i < hi; i += 256)
        atomicAdd(&h[dst[i] >> 9], 1);
    __syncthreads();
    for (int i = t; i < NB; i += 256) histT[i * NBLK + blk] = h[i];
}

// ---- 3-kernel exclusive scan (n <= 65536) ---------------------------------
__global__ void scan_block(const int* __restrict__ cnt, int* __restrict__ off,
                           int* __restrict__ bsum, int n) {
    __shared__ int lds[256];
    int t = threadIdx.x;
    int i = blockIdx.x * 256 + t;
    int v = (i < n) ? cnt[i] : 0;
    lds[t] = v;
    __syncthreads();
    for (int d = 1; d < 256; d <<= 1) {
        int add = (t >= d) ? lds[t - d] : 0;
        __syncthreads();
        lds[t] += add;
        __syncthreads();
    }
    if (i < n) off[i] = lds[t] - v;
    if (t == 255) bsum[blockIdx.x] = lds[255];
}

__global__ void scan_top(const int* __restrict__ bsum, int* __restrict__ boff,
                         int* __restrict__ off, int nblocks, int n) {
    __shared__ int lds[256];
    int t = threadIdx.x;
    int v = (t < nblocks) ? bsum[t] : 0;
    lds[t] = v;
    __syncthreads();
    for (int d = 1; d < 256; d <<= 1) {
        int add = (t >= d) ? lds[t - d] : 0;
        __syncthreads();
        lds[t] += add;
        __syncthreads();
    }
    if (t < nblocks) boff[t] = lds[t] - v;
    if (t == 255) off[n] = lds[255];
}

__global__ void scan_add(int* __restrict__ off, const int* __restrict__ boff, int n) {
    int i = blockIdx.x * 256 + threadIdx.x;
    if (i < n) off[i] += boff[blockIdx.x];
}

// ---- scatter packed edges into private (block,bucket) runs ----------------
__global__ __launch_bounds__(256) void scatter_packed(const int* __restrict__ src,
        const int* __restrict__ dst, const int* __restrict__ P,
        unsigned* __restrict__ packed, int E, int NBLK, int NB) {
    __shared__ int cur[MAXB];
    int blk = blockIdx.x, t = threadIdx.x;
    for (int i = t; i < NB; i += 256) cur[i] = P[i * NBLK + blk];
    __syncthreads();
    int lo = blk * BLK_EDGES;
    int hi = min(E, lo + BLK_EDGES);
    for (int i = lo + t; i < hi; i += 256) {
        int d = dst[i];
        int pos = atomicAdd(&cur[d >> 9], 1);   // LDS atomic, block-local
        packed[pos] = ((unsigned)d << 16) | (unsigned)src[i];
    }
}

// ---- per-bucket: node counts, local scan -> off/dis, fill ushort CSR ------
__global__ __launch_bounds__(256) void bucket_build(const unsigned* __restrict__ packed,
        const int* __restrict__ P, int* __restrict__ off, float* __restrict__ dis,
        unsigned short* __restrict__ csr16, int E, int NBLK, int N, int NB) {
    __shared__ int cnt[512];
    __shared__ int loc[512];
    __shared__ int ps[256];
    int b = blockIdx.x, t = threadIdx.x;
    int start = P[b * NBLK];
    int end   = P[(b + 1) * NBLK];
    cnt[t] = 0; cnt[t + 256] = 0;
    __syncthreads();
    for (int i = start + t; i < end; i += 256)
        atomicAdd(&cnt[(packed[i] >> 16) & 511], 1);
    __syncthreads();
    int c0 = cnt[2 * t], c1 = cnt[2 * t + 1];
    ps[t] = c0 + c1;
    __syncthreads();
    for (int d = 1; d < 256; d <<= 1) {
        int add = (t >= d) ? ps[t - d] : 0;
        __syncthreads();
        ps[t] += add;
        __syncthreads();
    }
    int pexcl = ps[t] - (c0 + c1);
    loc[2 * t]     = start + pexcl;
    loc[2 * t + 1] = start + pexcl + c0;
    __syncthreads();
    int node0 = b * 512;
    for (int l = t; l < 512; l += 256) {
        int node = node0 + l;
        if (node < N) {
            off[node] = loc[l];
            dis[node] = rsqrtf((float)cnt[l] + 1.0f);
        }
    }
    if (b == NB - 1 && t == 0) off[N] = E;
    __syncthreads();
    for (int i = start + t; i < end; i += 256) {
        unsigned p = packed[i];
        int l = (p >> 16) & 511;
        int pos = atomicAdd(&loc[l], 1);
        csr16[pos] = (unsigned short)(p & 0xFFFFu);
    }
}

// ---- fp32 -> bf16 convert (x into the act buffer) -------------------------
__global__ void tobf16(const float* __restrict__ x, unsigned short* __restrict__ xb,
                       int n4) {
    int i = blockIdx.x * 256 + threadIdx.x;
    if (i < n4) {
        float4 f = ((const float4*)x)[i];
        ushort4 o = {f2bf(f.x), f2bf(f.y), f2bf(f.z), f2bf(f.w)};
        ((ushort4*)xb)[i] = o;
    }
}

// ---- W [128 in][128 out] fp32 -> Wt [128 out][128 in] bf16 ----------------
__global__ void wtrans(const float* __restrict__ W, unsigned short* __restrict__ Wt) {
    int i = blockIdx.x * 256 + threadIdx.x;   // grid 64 -> 16384
    int k = i >> 7, n2 = i & 127;
    Wt[n2 * 128 + k] = f2bf(W[k * 128 + n2]);
}

// ---- MFMA GEMM: Hs16[r] = bf16( dis[r] * (A16[r] @ W) ) -------------------
// A16 bf16 [n][128]; Wt bf16 [128 out][128 in]. 128 threads = 2 waves,
// 64 rows/block (grid 782). W^T in LDS (stride 136); A-frags global->VGPR
// with row clamp. Epilogue IEEE-sanitized.
// Layouts: A[m=lane&15][k=quad*8+j], B[n=lane&15][k=quad*8+j],
// C/D[row=quad*4+reg][col=lane&15].
__global__ __launch_bounds__(128) void gemm_mfma(const unsigned short* __restrict__ A16,
        const unsigned short* __restrict__ Wt, const float* __restrict__ dis,
        unsigned short* __restrict__ Hs16, int n) {
    __shared__ unsigned short Ws[128 * WS_STRIDE];   // 34.8 KB
    int t = threadIdx.x;
    // stage all 128 rows x 16 uint4 chunks (16B each) = full 256B per row
    for (int i = t; i < 128 * 16; i += 128) {
        int r = i >> 4, j = i & 15;
        uint4 u = ((const uint4*)(Wt + r * 128))[j];
        *(uint4*)&Ws[r * WS_STRIDE + j * 8] = u;
    }
    __syncthreads();

    int wave = t >> 6, lane = t & 63;
    int quad = lane >> 4, l16 = lane & 15;
    int row0 = blockIdx.x * 64 + wave * 32;

    int ra0 = row0 + l16;      if (ra0 >= n) ra0 = n - 1;   // clamp: results
    int ra1 = row0 + 16 + l16; if (ra1 >= n) ra1 = n - 1;   // discarded on write

    f32x4 acc[2][8];
    const f32x4 z = {0.f, 0.f, 0.f, 0.f};
#pragma unroll
    for (int mi = 0; mi < 2; ++mi)
#pragma unroll
        for (int ni = 0; ni < 8; ++ni) acc[mi][ni] = z;

#pragma unroll
    for (int ks = 0; ks < 4; ++ks) {
        int kof = ks * 32 + quad * 8;
        bf16x8 a0 = *(const bf16x8*)(A16 + (size_t)ra0 * 128 + kof);
        bf16x8 a1 = *(const bf16x8*)(A16 + (size_t)ra1 * 128 + kof);
        bf16x8 b[8];
#pragma unroll
        for (int ni = 0; ni < 8; ++ni)
            b[ni] = *(const bf16x8*)&Ws[(ni * 16 + l16) * WS_STRIDE + kof];
#pragma unroll
        for (int ni = 0; ni < 8; ++ni) {
            acc[0][ni] = __builtin_amdgcn_mfma_f32_16x16x32_bf16(a0, b[ni], acc[0][ni], 0, 0, 0);
            acc[1][ni] = __builtin_amdgcn_mfma_f32_16x16x32_bf16(a1, b[ni], acc[1][ni], 0, 0, 0);
        }
    }
#pragma unroll
    for (int mi = 0; mi < 2; ++mi) {
        int rb = row0 + mi * 16 + quad * 4;
#pragma unroll
        for (int reg = 0; reg < 4; ++reg) {
            int r = rb + reg;
            if (r < n) {
                float dv = dis[r];
#pragma unroll
                for (int ni = 0; ni < 8; ++ni) {
                    float v = acc[mi][ni][reg] * dv;
                    v = fminf(fmaxf(v, -1e30f), 1e30f);   // IEEE: drops NaN too
                    Hs16[(size_t)r * 128 + ni * 16 + l16] = f2bf(v);
                }
            }
        }
    }
}

// ---- pull aggregation (R6): LDS-staged indices + double-buffered gathers --
template<int DO_TANH, int OUT_BF16>
__global__ __launch_bounds__(256) void aggregate3(const unsigned short* __restrict__ hs,
    const unsigned short* __restrict__ csr, const int* __restrict__ off,
    const float* __restrict__ dis, const float* __restrict__ bias,
    void* __restrict__ outp, int n) {
    __shared__ unsigned short eidx[ECAP];
    int t = threadIdx.x;
    int node0 = blockIdx.x * 4;
    int b0 = off[node0];
    int top = node0 + 4 < n ? node0 + 4 : n;
    int b4 = off[top];
    int mblk = b4 - b0;
    bool staged = (mblk <= ECAP);
    if (staged)
        for (int i = t; i < mblk; i += 256) eidx[i] = csr[b0 + i];
    __syncthreads();

    int node = node0 + (t >> 6);
    if (node >= n) return;
    int lane = t & 63;
    int half = lane >> 5;
    int fq = lane & 31;
    const uint2* H = (const uint2*)hs;

    int e0 = off[node];
    int e1 = off[node + 1];
    int le0 = e0 - b0;
    int m = e1 - e0;
    float ax = 0.f, ay = 0.f, az = 0.f, aw = 0.f;

    uint2 va[8], vb[8];
    auto sumB = [&](uint2* v) {
#pragma unroll
        for (int j = 0; j < 8; ++j) {
            ax += bf_lo(v[j].x); ay += bf_hi(v[j].x);
            az += bf_lo(v[j].y); aw += bf_hi(v[j].y);
        }
    };
    auto loadL = [&](int i, uint2* v) {
        int s[8];
#pragma unroll
        for (int j = 0; j < 8; ++j) s[j] = eidx[le0 + i + half + 2 * j];
#pragma unroll
        for (int j = 0; j < 8; ++j) v[j] = H[(size_t)s[j] * 32 + fq];
    };
    auto loadG = [&](int i, uint2* v) {
        int s[8];
#pragma unroll
        for (int j = 0; j < 8; ++j) s[j] = csr[e0 + i + half + 2 * j];
#pragma unroll
        for (int j = 0; j < 8; ++j) v[j] = H[(size_t)s[j] * 32 + fq];
    };

    int nfull = m & ~15;
    if (staged) {
        if (nfull) {
            int B = nfull >> 4;
            loadL(0, va);
            int k = 1;
            for (; k + 1 < B; k += 2) {
                loadL(k << 4, vb);       sumB(va);
                loadL((k + 1) << 4, va); sumB(vb);
            }
            if (k < B) { loadL(k << 4, vb); sumB(va); sumB(vb); }
            else       { sumB(va); }
        }
        for (int e = nfull + half; e < m; e += 2) {
            int s = eidx[le0 + e];
            uint2 v = H[(size_t)s * 32 + fq];
            ax += bf_lo(v.x); ay += bf_hi(v.x);
            az += bf_lo(v.y); aw += bf_hi(v.y);
        }
    } else {
        if (nfull) {
            int B = nfull >> 4;
            loadG(0, va);
            int k = 1;
            for (; k + 1 < B; k += 2) {
                loadG(k << 4, vb);       sumB(va);
                loadG((k + 1) << 4, va); sumB(vb);
            }
            if (k < B) { loadG(k << 4, vb); sumB(va); sumB(vb); }
            else       { sumB(va); }
        }
        for (int e = nfull + half; e < m; e += 2) {
            int s = csr[e0 + e];
            uint2 v = H[(size_t)s * 32 + fq];
            ax += bf_lo(v.x); ay += bf_hi(v.x);
            az += bf_lo(v.y); aw += bf_hi(v.y);
        }
    }

    ax += __shfl_xor(ax, 32, 64);
    ay += __shfl_xor(ay, 32, 64);
    az += __shfl_xor(az, 32, 64);
    aw += __shfl_xor(aw, 32, 64);

    uint2 sv = H[(size_t)node * 32 + fq];   // self loop (row pre-scaled by dn)
    ax += bf_lo(sv.x); ay += bf_hi(sv.x);
    az += bf_lo(sv.y); aw += bf_hi(sv.y);

    float dn = dis[node];
    float4 bv = ((const float4*)bias)[fq];
    float ox = fmaf(dn, ax, bv.x);
    float oy = fmaf(dn, ay, bv.y);
    float oz = fmaf(dn, az, bv.z);
    float ow = fmaf(dn, aw, bv.w);
    if (DO_TANH) {
        ox = tanhf(ox); oy = tanhf(oy); oz = tanhf(oz); ow = tanhf(ow);
    }
    if (half == 0) {
        if (OUT_BF16) {
            uint2 o;
            o.x = (unsigned)f2bf(ox) | ((unsigned)f2bf(oy) << 16);
            o.y = (unsigned)f2bf(oz) | ((unsigned)f2bf(ow) << 16);
            ((uint2*)outp)[(size_t)node * 32 + fq] = o;
        } else {
            float4 o = {ox, oy, oz, ow};
            *(float4*)((float*)outp + (size_t)node * 128 + fq * 4) = o;
        }
    }
}

// ---- per-graph node ranges via binary search on sorted batch --------------
__global__ void graph_starts(const int* __restrict__ batch, int* __restrict__ gstart,
                             int n, int G) {
    int g = blockIdx.x * 64 + threadIdx.x;
    if (g > G) return;
    int lo = 0, hi = n;
    while (lo < hi) {
        int mid = (lo + hi) >> 1;
        if (batch[mid] < g) lo = mid + 1; else hi = mid;
    }
    gstart[g] = lo;
}

__global__ __launch_bounds__(64) void pool_mean(const float* __restrict__ act,
    const int* __restrict__ gstart, float* __restrict__ pooled, int G) {
    int g = blockIdx.x;
    int l = threadIdx.x;
    int lo = gstart[g], hi = gstart[g + 1];
    float accx = 0.f, accy = 0.f;
    for (int i = lo; i < hi; ++i) {
        const float2 v = *(const float2*)(act + (size_t)i * 128 + l * 2);
        accx += v.x;
        accy += v.y;
    }
    int cnt = hi - lo;
    float inv = 1.0f / (float)(cnt > 0 ? cnt : 1);
    pooled[(size_t)g * 128 + 2 * l]     = accx * inv;
    pooled[(size_t)g * 128 + 2 * l + 1] = accy * inv;
}

__global__ __launch_bounds__(64) void head_kernel(const float* __restrict__ pooled,
    const float* __restrict__ Wout, const float* __restrict__ bout,
    float* __restrict__ out, int C) {
    __shared__ float l[16];
    __shared__ float stats[2];
    int g = blockIdx.x;
    int t = threadIdx.x;
    if (t < C) {
        float acc = bout[t];
        for (int f = 0; f < 128; ++f)
            acc = fmaf(pooled[(size_t)g * 128 + f], Wout[(size_t)f * C + t], acc);
        l[t] = acc;
    }
    __syncthreads();
    if (t == 0) {
        float m = -1e30f;
        for (int c = 0; c < C; ++c) m = fmaxf(m, l[c]);
        float s = 0.f;
        for (int c = 0; c < C; ++c) s += expf(l[c] - m);
        stats[0] = m;
        stats[1] = logf(s);
    }
    __syncthreads();
    if (t < C) out[(size_t)g * C + t] = l[t] - stats[0] - stats[1];
}

// ---------------------------------------------------------------------------
extern "C" void kernel_launch(void* const* d_in, const int* in_sizes, int n_in,
                              void* d_out, int out_size, void* d_ws, size_t ws_size,
                              hipStream_t stream) {
    const float* x     = (const float*)d_in[0];
    const int*   edge  = (const int*)d_in[1];
    const int*   batch = (const int*)d_in[2];
    const float* W0 = (const float*)d_in[3];
    const float* b0 = (const float*)d_in[4];
    const float* W1 = (const float*)d_in[5];
    const float* b1 = (const float*)d_in[6];
    const float* W2 = (const float*)d_in[7];
    const float* b2 = (const float*)d_in[8];
    const float* Wout = (const float*)d_in[9];
    const float* bout = (const float*)d_in[10];
    float* out = (float*)d_out;

    const int N = in_sizes[0] / 128;   // 50000 (< 65536 required for packing)
    const int E = in_sizes[1] / 2;     // 1600000
    const int C = in_sizes[10];        // 10
    const int G = out_size / C;        // 512

    const int* src = edge;
    const int* dst = edge + E;

    const int NBLK = (E + BLK_EDGES - 1) / BLK_EDGES;  // 391
    const int NB   = (N + 511) / 512;                  // 98 buckets
    const int NBQ  = NB * NBLK;                        // 38318 scan entries

    char* p = (char*)d_ws;
    auto alloc = [&](size_t bytes) -> void* {
        void* r = (void*)p;
        p += (bytes + 255) & ~(size_t)255;
        return r;
    };
    unsigned short* hs = (unsigned short*)alloc((size_t)N * 128 * 2);  // bf16 table
    float* act    = (float*)alloc((size_t)N * 128 * 4);  // bf16 x / bf16 act / fp32 act
    float* dis    = (float*)alloc((size_t)N * 4);
    int*   off    = (int*)alloc((size_t)(N + 1) * 4);
    int*   P      = (int*)alloc((size_t)(NBQ + 1) * 4);
    int*   bsum   = (int*)alloc(256 * 4);
    int*   boff   = (int*)alloc(256 * 4);
    unsigned* packed = (unsigned*)alloc((size_t)E * 4);
    unsigned short* csr16 = (unsigned short*)alloc((size_t)E * 2);
    unsigned short* wt0 = (unsigned short*)alloc(128 * 128 * 2);
    unsigned short* wt1 = (unsigned short*)alloc(128 * 128 * 2);
    unsigned short* wt2 = (unsigned short*)alloc(128 * 128 * 2);
    int*   gstart  = (int*)alloc((size_t)(G + 1) * 4);
    float* pooled  = (float*)alloc((size_t)G * 128 * 4);

    const int sb = (NBQ + 255) / 256;   // 150 (<=256 required by scan_top)

    // CSR build (no contended global atomics anywhere)
    blk_hist<<<NBLK, 256, 0, stream>>>(dst, P, E, NBLK, NB);
    scan_block<<<sb, 256, 0, stream>>>(P, P, bsum, NBQ);
    scan_top<<<1, 256, 0, stream>>>(bsum, boff, P, sb, NBQ);
    scan_add<<<sb, 256, 0, stream>>>(P, boff, NBQ);
    scatter_packed<<<NBLK, 256, 0, stream>>>(src, dst, P, packed, E, NBLK, NB);
    bucket_build<<<NB, 256, 0, stream>>>(packed, P, off, dis, csr16, E, NBLK, N, NB);

    // weight transposes + x -> bf16 (into act)
    wtrans<<<64, 256, 0, stream>>>(W0, wt0);
    wtrans<<<64, 256, 0, stream>>>(W1, wt1);
    wtrans<<<64, 256, 0, stream>>>(W2, wt2);
    unsigned short* actb = (unsigned short*)act;
    tobf16<<<(N * 32 + 255) / 256, 256, 0, stream>>>(x, actb, N * 32);

    const int gb = (N + 63) / 64;    // 782 blocks of 128 threads
    const int ab = (N + 3) / 4;

    gemm_mfma<<<gb, 128, 0, stream>>>(actb, wt0, dis, hs, N);
    aggregate3<1, 1><<<ab, 256, 0, stream>>>(hs, csr16, off, dis, b0, act, N);
    gemm_mfma<<<gb, 128, 0, stream>>>(actb, wt1, dis, hs, N);
    aggregate3<1, 1><<<ab, 256, 0, stream>>>(hs, csr16, off, dis, b1, act, N);
    gemm_mfma<<<gb, 128, 0, stream>>>(actb, wt2, dis, hs, N);
    aggregate3<0, 0><<<ab, 256, 0, stream>>>(hs, csr16, off, dis, b2, act, N);

    graph_starts<<<(G + 64) / 64, 64, 0, stream>>>(batch, gstart, N, G);
    pool_mean<<<G, 64, 0, stream>>>(act, gstart, pooled, G);
    head_kernel<<<G, 64, 0, stream>>>(pooled, Wout, bout, out, C);
}

// Round 11
// 403.183 us; speedup vs baseline: 1.3475x; 1.0502x over previous
//
#include <hip/hip_runtime.h>
#include <math.h>

// ---------------------------------------------------------------------------
// GCN: 3x (MFMA GEMM(+dis scale, bf16) -> pull-aggregate -> bias -> tanh)
//      -> fused pool+head
// R11: launch-count consolidation (19 -> 13): wtrans x3 + tobf16 fused into
//      prep; graph_starts+pool_mean+head fused into pool_head; scan_add
//      removed by folding boff into scatter_packed/bucket_build cursor math.
//      Hot kernels (gemm_mfma, aggregate3) byte-identical to R10.
// ---------------------------------------------------------------------------

#define BLK_EDGES 4096
#define MAXB 128          // max dst-buckets for CSR build (N<=65536)
#define ECAP 2048         // LDS edge-index capacity per aggregate block
#define WS_STRIDE 136     // LDS row stride for W^T (elements; 272B, 16B-aligned)

typedef __attribute__((ext_vector_type(8))) short bf16x8;
typedef __attribute__((ext_vector_type(4))) float f32x4;

static __device__ inline unsigned short f2bf(float f) {
    unsigned u = __float_as_uint(f);
    unsigned r = (u + 0x7FFFu + ((u >> 16) & 1u)) >> 16;   // RNE
    return (unsigned short)r;
}
static __device__ inline float bf_lo(unsigned u) { return __uint_as_float(u << 16); }
static __device__ inline float bf_hi(unsigned u) { return __uint_as_float(u & 0xFFFF0000u); }

// ---- per-block bucket histogram (bucket = dst >> 9), transposed output ----
__global__ __launch_bounds__(256) void blk_hist(const int* __restrict__ dst,
        int* __restrict__ histT, int E, int NBLK, int NB) {
    __shared__ int h[MAXB];
    int blk = blockIdx.x, t = threadIdx.x;
    for (int i = t; i < NB; i += 256) h[i] = 0;
    __syncthreads();
    int lo = blk * BLK_EDGES;
    int hi = min(E, lo + BLK_EDGES);
    for (int i = lo + t; i < hi; i += 256)
        atomicAdd(&h[dst[i] >> 9], 1);
    __syncthreads();
    for (int i = t; i < NB; i += 256) histT[i * NBLK + blk] = h[i];
}

// ---- 2-kernel scan (per-chunk exclusive + chunk offsets; consumers fold) --
__global__ void scan_block(const int* __restrict__ cnt, int* __restrict__ off,
                           int* __restrict__ bsum, int n) {
    __shared__ int lds[256];
    int t = threadIdx.x;
    int i = blockIdx.x * 256 + t;
    int v = (i < n) ? cnt[i] : 0;
    lds[t] = v;
    __syncthreads();
    for (int d = 1; d < 256; d <<= 1) {
        int add = (t >= d) ? lds[t - d] : 0;
        __syncthreads();
        lds[t] += add;
        __syncthreads();
    }
    if (i < n) off[i] = lds[t] - v;      // exclusive within 256-chunk
    if (t == 255) bsum[blockIdx.x] = lds[255];
}

__global__ void scan_top(const int* __restrict__ bsum, int* __restrict__ boff,
                         int nblocks) {
    __shared__ int lds[256];
    int t = threadIdx.x;
    int v = (t < nblocks) ? bsum[t] : 0;
    lds[t] = v;
    __syncthreads();
    for (int d = 1; d < 256; d <<= 1) {
        int add = (t >= d) ? lds[t - d] : 0;
        __syncthreads();
        lds[t] += add;
        __syncthreads();
    }
    if (t < nblocks) boff[t] = lds[t] - v;   // exclusive chunk offsets
}

// ---- scatter packed edges into private (block,bucket) runs ----------------
// P holds per-chunk-exclusive scan; global base = P[idx] + boff[idx>>8].
__global__ __launch_bounds__(256) void scatter_packed(const int* __restrict__ src,
        const int* __restrict__ dst, const int* __restrict__ P,
        const int* __restrict__ boff, unsigned* __restrict__ packed,
        int E, int NBLK, int NB) {
    __shared__ int cur[MAXB];
    int blk = blockIdx.x, t = threadIdx.x;
    for (int i = t; i < NB; i += 256) {
        int idx = i * NBLK + blk;
        cur[i] = P[idx] + boff[idx >> 8];
    }
    __syncthreads();
    int lo = blk * BLK_EDGES;
    int hi = min(E, lo + BLK_EDGES);
    for (int i = lo + t; i < hi; i += 256) {
        int d = dst[i];
        int pos = atomicAdd(&cur[d >> 9], 1);   // LDS atomic, block-local
        packed[pos] = ((unsigned)d << 16) | (unsigned)src[i];
    }
}

// ---- per-bucket: node counts, local scan -> off/dis, fill ushort CSR ------
__global__ __launch_bounds__(256) void bucket_build(const unsigned* __restrict__ packed,
        const int* __restrict__ P, const int* __restrict__ boff, int* __restrict__ off,
        float* __restrict__ dis, unsigned short* __restrict__ csr16,
        int E, int NBLK, int N, int NB) {
    __shared__ int cnt[512];
    __shared__ int loc[512];
    __shared__ int ps[256];
    int b = blockIdx.x, t = threadIdx.x;
    int i0 = b * NBLK, i1 = (b + 1) * NBLK;
    int start = P[i0] + boff[i0 >> 8];
    int end   = (b == NB - 1) ? E : (P[i1] + boff[i1 >> 8]);
    cnt[t] = 0; cnt[t + 256] = 0;
    __syncthreads();
    for (int i = start + t; i < end; i += 256)
        atomicAdd(&cnt[(packed[i] >> 16) & 511], 1);
    __syncthreads();
    int c0 = cnt[2 * t], c1 = cnt[2 * t + 1];
    ps[t] = c0 + c1;
    __syncthreads();
    for (int d = 1; d < 256; d <<= 1) {
        int add = (t >= d) ? ps[t - d] : 0;
        __syncthreads();
        ps[t] += add;
        __syncthreads();
    }
    int pexcl = ps[t] - (c0 + c1);
    loc[2 * t]     = start + pexcl;
    loc[2 * t + 1] = start + pexcl + c0;
    __syncthreads();
    int node0 = b * 512;
    for (int l = t; l < 512; l += 256) {
        int node = node0 + l;
        if (node < N) {
            off[node] = loc[l];
            dis[node] = rsqrtf((float)cnt[l] + 1.0f);
        }
    }
    if (b == NB - 1 && t == 0) off[N] = E;
    __syncthreads();
    for (int i = start + t; i < end; i += 256) {
        unsigned p = packed[i];
        int l = (p >> 16) & 511;
        int pos = atomicAdd(&loc[l], 1);
        csr16[pos] = (unsigned short)(p & 0xFFFFu);
    }
}

// ---- prep: 3x W transpose->bf16 + x->bf16, one launch ---------------------
__global__ __launch_bounds__(256) void prep(const float* __restrict__ W0,
        const float* __restrict__ W1, const float* __restrict__ W2,
        unsigned short* __restrict__ wt0, unsigned short* __restrict__ wt1,
        unsigned short* __restrict__ wt2, const float* __restrict__ x,
        unsigned short* __restrict__ xb, int n4) {
    int i = blockIdx.x * 256 + threadIdx.x;
    if (i < 3 * 16384) {
        int w = i >> 14, j = i & 16383;
        int k = j >> 7, n2 = j & 127;
        const float* Wp = (w == 0) ? W0 : (w == 1) ? W1 : W2;
        unsigned short* Wt = (w == 0) ? wt0 : (w == 1) ? wt1 : wt2;
        Wt[n2 * 128 + k] = f2bf(Wp[k * 128 + n2]);
    } else {
        int j = i - 3 * 16384;
        if (j < n4) {
            float4 f = ((const float4*)x)[j];
            ushort4 o = {f2bf(f.x), f2bf(f.y), f2bf(f.z), f2bf(f.w)};
            ((ushort4*)xb)[j] = o;
        }
    }
}

// ---- MFMA GEMM: Hs16[r] = bf16( dis[r] * (A16[r] @ W) ) -------------------
// A16 bf16 [n][128]; Wt bf16 [128 out][128 in]. 128 threads = 2 waves,
// 64 rows/block. W^T in LDS (stride 136); A-frags global->VGPR, row-clamped.
// Layouts: A[m=lane&15][k=quad*8+j], B[n=lane&15][k=quad*8+j],
// C/D[row=quad*4+reg][col=lane&15].
__global__ __launch_bounds__(128) void gemm_mfma(const unsigned short* __restrict__ A16,
        const unsigned short* __restrict__ Wt, const float* __restrict__ dis,
        unsigned short* __restrict__ Hs16, int n) {
    __shared__ unsigned short Ws[128 * WS_STRIDE];   // 34.8 KB
    int t = threadIdx.x;
    for (int i = t; i < 128 * 16; i += 128) {
        int r = i >> 4, j = i & 15;
        uint4 u = ((const uint4*)(Wt + r * 128))[j];
        *(uint4*)&Ws[r * WS_STRIDE + j * 8] = u;
    }
    __syncthreads();

    int wave = t >> 6, lane = t & 63;
    int quad = lane >> 4, l16 = lane & 15;
    int row0 = blockIdx.x * 64 + wave * 32;

    int ra0 = row0 + l16;      if (ra0 >= n) ra0 = n - 1;
    int ra1 = row0 + 16 + l16; if (ra1 >= n) ra1 = n - 1;

    f32x4 acc[2][8];
    const f32x4 z = {0.f, 0.f, 0.f, 0.f};
#pragma unroll
    for (int mi = 0; mi < 2; ++mi)
#pragma unroll
        for (int ni = 0; ni < 8; ++ni) acc[mi][ni] = z;

#pragma unroll
    for (int ks = 0; ks < 4; ++ks) {
        int kof = ks * 32 + quad * 8;
        bf16x8 a0 = *(const bf16x8*)(A16 + (size_t)ra0 * 128 + kof);
        bf16x8 a1 = *(const bf16x8*)(A16 + (size_t)ra1 * 128 + kof);
        bf16x8 b[8];
#pragma unroll
        for (int ni = 0; ni < 8; ++ni)
            b[ni] = *(const bf16x8*)&Ws[(ni * 16 + l16) * WS_STRIDE + kof];
#pragma unroll
        for (int ni = 0; ni < 8; ++ni) {
            acc[0][ni] = __builtin_amdgcn_mfma_f32_16x16x32_bf16(a0, b[ni], acc[0][ni], 0, 0, 0);
            acc[1][ni] = __builtin_amdgcn_mfma_f32_16x16x32_bf16(a1, b[ni], acc[1][ni], 0, 0, 0);
        }
    }
#pragma unroll
    for (int mi = 0; mi < 2; ++mi) {
        int rb = row0 + mi * 16 + quad * 4;
#pragma unroll
        for (int reg = 0; reg < 4; ++reg) {
            int r = rb + reg;
            if (r < n) {
                float dv = dis[r];
#pragma unroll
                for (int ni = 0; ni < 8; ++ni) {
                    float v = acc[mi][ni][reg] * dv;
                    v = fminf(fmaxf(v, -1e30f), 1e30f);   // drops NaN too
                    Hs16[(size_t)r * 128 + ni * 16 + l16] = f2bf(v);
                }
            }
        }
    }
}

// ---- pull aggregation (R6): LDS-staged indices + double-buffered gathers --
template<int DO_TANH, int OUT_BF16>
__global__ __launch_bounds__(256) void aggregate3(const unsigned short* __restrict__ hs,
    const unsigned short* __restrict__ csr, const int* __restrict__ off,
    const float* __restrict__ dis, const float* __restrict__ bias,
    void* __restrict__ outp, int n) {
    __shared__ unsigned short eidx[ECAP];
    int t = threadIdx.x;
    int node0 = blockIdx.x * 4;
    int b0 = off[node0];
    int top = node0 + 4 < n ? node0 + 4 : n;
    int b4 = off[top];
    int mblk = b4 - b0;
    bool staged = (mblk <= ECAP);
    if (staged)
        for (int i = t; i < mblk; i += 256) eidx[i] = csr[b0 + i];
    __syncthreads();

    int node = node0 + (t >> 6);
    if (node >= n) return;
    int lane = t & 63;
    int half = lane >> 5;
    int fq = lane & 31;
    const uint2* H = (const uint2*)hs;

    int e0 = off[node];
    int e1 = off[node + 1];
    int le0 = e0 - b0;
    int m = e1 - e0;
    float ax = 0.f, ay = 0.f, az = 0.f, aw = 0.f;

    uint2 va[8], vb[8];
    auto sumB = [&](uint2* v) {
#pragma unroll
        for (int j = 0; j < 8; ++j) {
            ax += bf_lo(v[j].x); ay += bf_hi(v[j].x);
            az += bf_lo(v[j].y); aw += bf_hi(v[j].y);
        }
    };
    auto loadL = [&](int i, uint2* v) {
        int s[8];
#pragma unroll
        for (int j = 0; j < 8; ++j) s[j] = eidx[le0 + i + half + 2 * j];
#pragma unroll
        for (int j = 0; j < 8; ++j) v[j] = H[(size_t)s[j] * 32 + fq];
    };
    auto loadG = [&](int i, uint2* v) {
        int s[8];
#pragma unroll
        for (int j = 0; j < 8; ++j) s[j] = csr[e0 + i + half + 2 * j];
#pragma unroll
        for (int j = 0; j < 8; ++j) v[j] = H[(size_t)s[j] * 32 + fq];
    };

    int nfull = m & ~15;
    if (staged) {
        if (nfull) {
            int B = nfull >> 4;
            loadL(0, va);
            int k = 1;
            for (; k + 1 < B; k += 2) {
                loadL(k << 4, vb);       sumB(va);
                loadL((k + 1) << 4, va); sumB(vb);
            }
            if (k < B) { loadL(k << 4, vb); sumB(va); sumB(vb); }
            else       { sumB(va); }
        }
        for (int e = nfull + half; e < m; e += 2) {
            int s = eidx[le0 + e];
            uint2 v = H[(size_t)s * 32 + fq];
            ax += bf_lo(v.x); ay += bf_hi(v.x);
            az += bf_lo(v.y); aw += bf_hi(v.y);
        }
    } else {
        if (nfull) {
            int B = nfull >> 4;
            loadG(0, va);
            int k = 1;
            for (; k + 1 < B; k += 2) {
                loadG(k << 4, vb);       sumB(va);
                loadG((k + 1) << 4, va); sumB(vb);
            }
            if (k < B) { loadG(k << 4, vb); sumB(va); sumB(vb); }
            else       { sumB(va); }
        }
        for (int e = nfull + half; e < m; e += 2) {
            int s = csr[e0 + e];
            uint2 v = H[(size_t)s * 32 + fq];
            ax += bf_lo(v.x); ay += bf_hi(v.x);
            az += bf_lo(v.y); aw += bf_hi(v.y);
        }
    }

    ax += __shfl_xor(ax, 32, 64);
    ay += __shfl_xor(ay, 32, 64);
    az += __shfl_xor(az, 32, 64);
    aw += __shfl_xor(aw, 32, 64);

    uint2 sv = H[(size_t)node * 32 + fq];   // self loop (row pre-scaled by dn)
    ax += bf_lo(sv.x); ay += bf_hi(sv.x);
    az += bf_lo(sv.y); aw += bf_hi(sv.y);

    float dn = dis[node];
    float4 bv = ((const float4*)bias)[fq];
    float ox = fmaf(dn, ax, bv.x);
    float oy = fmaf(dn, ay, bv.y);
    float oz = fmaf(dn, az, bv.z);
    float ow = fmaf(dn, aw, bv.w);
    if (DO_TANH) {
        ox = tanhf(ox); oy = tanhf(oy); oz = tanhf(oz); ow = tanhf(ow);
    }
    if (half == 0) {
        if (OUT_BF16) {
            uint2 o;
            o.x = (unsigned)f2bf(ox) | ((unsigned)f2bf(oy) << 16);
            o.y = (unsigned)f2bf(oz) | ((unsigned)f2bf(ow) << 16);
            ((uint2*)outp)[(size_t)node * 32 + fq] = o;
        } else {
            float4 o = {ox, oy, oz, ow};
            *(float4*)((float*)outp + (size_t)node * 128 + fq * 4) = o;
        }
    }
}

// ---- fused pool + head: one block (64 threads) per graph ------------------
__global__ __launch_bounds__(64) void pool_head(const float* __restrict__ act,
    const int* __restrict__ batch, const float* __restrict__ Wout,
    const float* __restrict__ bout, float* __restrict__ out, int n, int C) {
    __shared__ float pooled[128];
    __shared__ float l[16];
    __shared__ float stats[2];
    int g = blockIdx.x;
    int t = threadIdx.x;
    // bounds via binary search on sorted batch (each thread computes both)
    int lo = 0, hi = n;
    while (lo < hi) { int mid = (lo + hi) >> 1; if (batch[mid] < g) lo = mid + 1; else hi = mid; }
    int lo1 = lo, hi1 = n;
    while (lo1 < hi1) { int mid = (lo1 + hi1) >> 1; if (batch[mid] < g + 1) lo1 = mid + 1; else hi1 = mid; }
    float ax = 0.f, ay = 0.f;
    for (int i = lo; i < lo1; ++i) {
        const float2 v = *(const float2*)(act + (size_t)i * 128 + t * 2);
        ax += v.x;
        ay += v.y;
    }
    int cnt = lo1 - lo;
    float inv = 1.0f / (float)(cnt > 0 ? cnt : 1);
    pooled[2 * t]     = ax * inv;
    pooled[2 * t + 1] = ay * inv;
    __syncthreads();
    if (t < C) {
        float acc = bout[t];
        for (int f = 0; f < 128; ++f)
            acc = fmaf(pooled[f], Wout[(size_t)f * C + t], acc);
        l[t] = acc;
    }
    __syncthreads();
    if (t == 0) {
        float m = -1e30f;
        for (int c = 0; c < C; ++c) m = fmaxf(m, l[c]);
        float s = 0.f;
        for (int c = 0; c < C; ++c) s += expf(l[c] - m);
        stats[0] = m;
        stats[1] = logf(s);
    }
    __syncthreads();
    if (t < C) out[(size_t)g * C + t] = l[t] - stats[0] - stats[1];
}

// ---------------------------------------------------------------------------
extern "C" void kernel_launch(void* const* d_in, const int* in_sizes, int n_in,
                              void* d_out, int out_size, void* d_ws, size_t ws_size,
                              hipStream_t stream) {
    const float* x     = (const float*)d_in[0];
    const int*   edge  = (const int*)d_in[1];
    const int*   batch = (const int*)d_in[2];
    const float* W0 = (const float*)d_in[3];
    const float* b0 = (const float*)d_in[4];
    const float* W1 = (const float*)d_in[5];
    const float* b1 = (const float*)d_in[6];
    const float* W2 = (const float*)d_in[7];
    const float* b2 = (const float*)d_in[8];
    const float* Wout = (const float*)d_in[9];
    const float* bout = (const float*)d_in[10];
    float* out = (float*)d_out;

    const int N = in_sizes[0] / 128;   // 50000 (< 65536 required for packing)
    const int E = in_sizes[1] / 2;     // 1600000
    const int C = in_sizes[10];        // 10
    const int G = out_size / C;        // 512

    const int* src = edge;
    const int* dst = edge + E;

    const int NBLK = (E + BLK_EDGES - 1) / BLK_EDGES;  // 391
    const int NB   = (N + 511) / 512;                  // 98 buckets
    const int NBQ  = NB * NBLK;                        // 38318 scan entries

    char* p = (char*)d_ws;
    auto alloc = [&](size_t bytes) -> void* {
        void* r = (void*)p;
        p += (bytes + 255) & ~(size_t)255;
        return r;
    };
    unsigned short* hs = (unsigned short*)alloc((size_t)N * 128 * 2);  // bf16 table
    float* act    = (float*)alloc((size_t)N * 128 * 4);  // bf16 x / bf16 act / fp32 act
    float* dis    = (float*)alloc((size_t)N * 4);
    int*   off    = (int*)alloc((size_t)(N + 1) * 4);
    int*   P      = (int*)alloc((size_t)(NBQ + 1) * 4);
    int*   bsum   = (int*)alloc(256 * 4);
    int*   boff   = (int*)alloc(256 * 4);
    unsigned* packed = (unsigned*)alloc((size_t)E * 4);
    unsigned short* csr16 = (unsigned short*)alloc((size_t)E * 2);
    unsigned short* wt0 = (unsigned short*)alloc(128 * 128 * 2);
    unsigned short* wt1 = (unsigned short*)alloc(128 * 128 * 2);
    unsigned short* wt2 = (unsigned short*)alloc(128 * 128 * 2);

    const int sb = (NBQ + 255) / 256;   // 150 (<=256 required by scan_top)

    // CSR build (no contended global atomics anywhere)
    blk_hist<<<NBLK, 256, 0, stream>>>(dst, P, E, NBLK, NB);
    scan_block<<<sb, 256, 0, stream>>>(P, P, bsum, NBQ);
    scan_top<<<1, 256, 0, stream>>>(bsum, boff, sb);
    scatter_packed<<<NBLK, 256, 0, stream>>>(src, dst, P, boff, packed, E, NBLK, NB);
    bucket_build<<<NB, 256, 0, stream>>>(packed, P, boff, off, dis, csr16, E, NBLK, N, NB);

    // weights -> bf16 transposed + x -> bf16 (into act), single launch
    unsigned short* actb = (unsigned short*)act;
    const int n4 = N * 32;
    prep<<<(3 * 16384 + n4 + 255) / 256, 256, 0, stream>>>(W0, W1, W2, wt0, wt1, wt2,
                                                           x, actb, n4);

    const int gb = (N + 63) / 64;    // 782 blocks of 128 threads
    const int ab = (N + 3) / 4;

    gemm_mfma<<<gb, 128, 0, stream>>>(actb, wt0, dis, hs, N);
    aggregate3<1, 1><<<ab, 256, 0, stream>>>(hs, csr16, off, dis, b0, act, N);
    gemm_mfma<<<gb, 128, 0, stream>>>(actb, wt1, dis, hs, N);
    aggregate3<1, 1><<<ab, 256, 0, stream>>>(hs, csr16, off, dis, b1, act, N);
    gemm_mfma<<<gb, 128, 0, stream>>>(actb, wt2, dis, hs, N);
    aggregate3<0, 0><<<ab, 256, 0, stream>>>(hs, csr16, off, dis, b2, act, N);

    pool_head<<<G, 64, 0, stream>>>(act, batch, Wout, bout, out, N, C);
}

// Round 12
// 361.099 us; speedup vs baseline: 1.5045x; 1.1165x over previous
//
#include <hip/hip_runtime.h>
#include <math.h>

// ---------------------------------------------------------------------------
// GCN: 3x (MFMA GEMM(+dis scale, fp8 table out) -> pull-aggregate -> tanh)
//      -> fused pool+head
// R12: gather table hs in fp8 e4m3 (128 B/row vs 256): halves L2-miss lines,
//      halves the 8x-XCD replication floor, table ~fits one XCD L2.
//      Only the aggregation sum reads fp8; act/weights/GEMM stay bf16.
//      Structure otherwise identical to R11.
// ---------------------------------------------------------------------------

#define BLK_EDGES 4096
#define MAXB 128          // max dst-buckets for CSR build (N<=65536)
#define ECAP 2048         // LDS edge-index capacity per aggregate block
#define WS_STRIDE 136     // LDS row stride for W^T (elements; 272B, 16B-aligned)

typedef __attribute__((ext_vector_type(8))) short bf16x8;
typedef __attribute__((ext_vector_type(4))) float f32x4;

static __device__ inline unsigned short f2bf(float f) {
    unsigned u = __float_as_uint(f);
    unsigned r = (u + 0x7FFFu + ((u >> 16) & 1u)) >> 16;   // RNE
    return (unsigned short)r;
}
static __device__ inline float bf_lo(unsigned u) { return __uint_as_float(u << 16); }
static __device__ inline float bf_hi(unsigned u) { return __uint_as_float(u & 0xFFFF0000u); }
static __device__ inline unsigned char f2fp8(float v) {
    v = fminf(fmaxf(v, -240.f), 240.f);                    // avoid e4m3 NaN
    int u = __builtin_amdgcn_cvt_pk_fp8_f32(v, v, 0, false);
    return (unsigned char)(u & 0xFF);
}

// ---- per-block bucket histogram (bucket = dst >> 9), transposed output ----
__global__ __launch_bounds__(256) void blk_hist(const int* __restrict__ dst,
        int* __restrict__ histT, int E, int NBLK, int NB) {
    __shared__ int h[MAXB];
    int blk = blockIdx.x, t = threadIdx.x;
    for (int i = t; i < NB; i += 256) h[i] = 0;
    __syncthreads();
    int lo = blk * BLK_EDGES;
    int hi = min(E, lo + BLK_EDGES);
    for (int i = lo + t; i < hi; i += 256)
        atomicAdd(&h[dst[i] >> 9], 1);
    __syncthreads();
    for (int i = t; i < NB; i += 256) histT[i * NBLK + blk] = h[i];
}

// ---- 2-kernel scan (per-chunk exclusive + chunk offsets; consumers fold) --
__global__ void scan_block(const int* __restrict__ cnt, int* __restrict__ off,
                           int* __restrict__ bsum, int n) {
    __shared__ int lds[256];
    int t = threadIdx.x;
    int i = blockIdx.x * 256 + t;
    int v = (i < n) ? cnt[i] : 0;
    lds[t] = v;
    __syncthreads();
    for (int d = 1; d < 256; d <<= 1) {
        int add = (t >= d) ? lds[t - d] : 0;
        __syncthreads();
        lds[t] += add;
        __syncthreads();
    }
    if (i < n) off[i] = lds[t] - v;      // exclusive within 256-chunk
    if (t == 255) bsum[blockIdx.x] = lds[255];
}

__global__ void scan_top(const int* __restrict__ bsum, int* __restrict__ boff,
                         int nblocks) {
    __shared__ int lds[256];
    int t = threadIdx.x;
    int v = (t < nblocks) ? bsum[t] : 0;
    lds[t] = v;
    __syncthreads();
    for (int d = 1; d < 256; d <<= 1) {
        int add = (t >= d) ? lds[t - d] : 0;
        __syncthreads();
        lds[t] += add;
        __syncthreads();
    }
    if (t < nblocks) boff[t] = lds[t] - v;   // exclusive chunk offsets
}

// ---- scatter packed edges into private (block,bucket) runs ----------------
__global__ __launch_bounds__(256) void scatter_packed(const int* __restrict__ src,
        const int* __restrict__ dst, const int* __restrict__ P,
        const int* __restrict__ boff, unsigned* __restrict__ packed,
        int E, int NBLK, int NB) {
    __shared__ int cur[MAXB];
    int blk = blockIdx.x, t = threadIdx.x;
    for (int i = t; i < NB; i += 256) {
        int idx = i * NBLK + blk;
        cur[i] = P[idx] + boff[idx >> 8];
    }
    __syncthreads();
    int lo = blk * BLK_EDGES;
    int hi = min(E, lo + BLK_EDGES);
    for (int i = lo + t; i < hi; i += 256) {
        int d = dst[i];
        int pos = atomicAdd(&cur[d >> 9], 1);   // LDS atomic, block-local
        packed[pos] = ((unsigned)d << 16) | (unsigned)src[i];
    }
}

// ---- per-bucket: node counts, local scan -> off/dis, fill ushort CSR ------
__global__ __launch_bounds__(256) void bucket_build(const unsigned* __restrict__ packed,
        const int* __restrict__ P, const int* __restrict__ boff, int* __restrict__ off,
        float* __restrict__ dis, unsigned short* __restrict__ csr16,
        int E, int NBLK, int N, int NB) {
    __shared__ int cnt[512];
    __shared__ int loc[512];
    __shared__ int ps[256];
    int b = blockIdx.x, t = threadIdx.x;
    int i0 = b * NBLK, i1 = (b + 1) * NBLK;
    int start = P[i0] + boff[i0 >> 8];
    int end   = (b == NB - 1) ? E : (P[i1] + boff[i1 >> 8]);
    cnt[t] = 0; cnt[t + 256] = 0;
    __syncthreads();
    for (int i = start + t; i < end; i += 256)
        atomicAdd(&cnt[(packed[i] >> 16) & 511], 1);
    __syncthreads();
    int c0 = cnt[2 * t], c1 = cnt[2 * t + 1];
    ps[t] = c0 + c1;
    __syncthreads();
    for (int d = 1; d < 256; d <<= 1) {
        int add = (t >= d) ? ps[t - d] : 0;
        __syncthreads();
        ps[t] += add;
        __syncthreads();
    }
    int pexcl = ps[t] - (c0 + c1);
    loc[2 * t]     = start + pexcl;
    loc[2 * t + 1] = start + pexcl + c0;
    __syncthreads();
    int node0 = b * 512;
    for (int l = t; l < 512; l += 256) {
        int node = node0 + l;
        if (node < N) {
            off[node] = loc[l];
            dis[node] = rsqrtf((float)cnt[l] + 1.0f);
        }
    }
    if (b == NB - 1 && t == 0) off[N] = E;
    __syncthreads();
    for (int i = start + t; i < end; i += 256) {
        unsigned p = packed[i];
        int l = (p >> 16) & 511;
        int pos = atomicAdd(&loc[l], 1);
        csr16[pos] = (unsigned short)(p & 0xFFFFu);
    }
}

// ---- prep: 3x W transpose->bf16 + x->bf16, one launch ---------------------
__global__ __launch_bounds__(256) void prep(const float* __restrict__ W0,
        const float* __restrict__ W1, const float* __restrict__ W2,
        unsigned short* __restrict__ wt0, unsigned short* __restrict__ wt1,
        unsigned short* __restrict__ wt2, const float* __restrict__ x,
        unsigned short* __restrict__ xb, int n4) {
    int i = blockIdx.x * 256 + threadIdx.x;
    if (i < 3 * 16384) {
        int w = i >> 14, j = i & 16383;
        int k = j >> 7, n2 = j & 127;
        const float* Wp = (w == 0) ? W0 : (w == 1) ? W1 : W2;
        unsigned short* Wt = (w == 0) ? wt0 : (w == 1) ? wt1 : wt2;
        Wt[n2 * 128 + k] = f2bf(Wp[k * 128 + n2]);
    } else {
        int j = i - 3 * 16384;
        if (j < n4) {
            float4 f = ((const float4*)x)[j];
            ushort4 o = {f2bf(f.x), f2bf(f.y), f2bf(f.z), f2bf(f.w)};
            ((ushort4*)xb)[j] = o;
        }
    }
}

// ---- MFMA GEMM: Hs8[r] = fp8( dis[r] * (A16[r] @ W) ) ---------------------
// A16 bf16 [n][128]; Wt bf16 [128 out][128 in]. 128 threads = 2 waves,
// 64 rows/block. W^T in LDS (stride 136); A-frags global->VGPR, row-clamped.
// Layouts: A[m=lane&15][k=quad*8+j], B[n=lane&15][k=quad*8+j],
// C/D[row=quad*4+reg][col=lane&15]. Output table fp8 e4m3 (128 B/row).
__global__ __launch_bounds__(128) void gemm_mfma(const unsigned short* __restrict__ A16,
        const unsigned short* __restrict__ Wt, const float* __restrict__ dis,
        unsigned char* __restrict__ Hs8, int n) {
    __shared__ unsigned short Ws[128 * WS_STRIDE];   // 34.8 KB
    int t = threadIdx.x;
    for (int i = t; i < 128 * 16; i += 128) {
        int r = i >> 4, j = i & 15;
        uint4 u = ((const uint4*)(Wt + r * 128))[j];
        *(uint4*)&Ws[r * WS_STRIDE + j * 8] = u;
    }
    __syncthreads();

    int wave = t >> 6, lane = t & 63;
    int quad = lane >> 4, l16 = lane & 15;
    int row0 = blockIdx.x * 64 + wave * 32;

    int ra0 = row0 + l16;      if (ra0 >= n) ra0 = n - 1;
    int ra1 = row0 + 16 + l16; if (ra1 >= n) ra1 = n - 1;

    f32x4 acc[2][8];
    const f32x4 z = {0.f, 0.f, 0.f, 0.f};
#pragma unroll
    for (int mi = 0; mi < 2; ++mi)
#pragma unroll
        for (int ni = 0; ni < 8; ++ni) acc[mi][ni] = z;

#pragma unroll
    for (int ks = 0; ks < 4; ++ks) {
        int kof = ks * 32 + quad * 8;
        bf16x8 a0 = *(const bf16x8*)(A16 + (size_t)ra0 * 128 + kof);
        bf16x8 a1 = *(const bf16x8*)(A16 + (size_t)ra1 * 128 + kof);
        bf16x8 b[8];
#pragma unroll
        for (int ni = 0; ni < 8; ++ni)
            b[ni] = *(const bf16x8*)&Ws[(ni * 16 + l16) * WS_STRIDE + kof];
#pragma unroll
        for (int ni = 0; ni < 8; ++ni) {
            acc[0][ni] = __builtin_amdgcn_mfma_f32_16x16x32_bf16(a0, b[ni], acc[0][ni], 0, 0, 0);
            acc[1][ni] = __builtin_amdgcn_mfma_f32_16x16x32_bf16(a1, b[ni], acc[1][ni], 0, 0, 0);
        }
    }
#pragma unroll
    for (int mi = 0; mi < 2; ++mi) {
        int rb = row0 + mi * 16 + quad * 4;
#pragma unroll
        for (int reg = 0; reg < 4; ++reg) {
            int r = rb + reg;
            if (r < n) {
                float dv = dis[r];
#pragma unroll
                for (int ni = 0; ni < 8; ++ni)
                    Hs8[(size_t)r * 128 + ni * 16 + l16] = f2fp8(acc[mi][ni][reg] * dv);
            }
        }
    }
}

// ---- pull aggregation over fp8 table: LDS indices + dbuf gathers ----------
// One wave per node; 2 half-wave edge streams; lane covers feats [4fq,4fq+4)
// via one uint (4 fp8) per gather; hw v_cvt_f32_fp8 decode.
template<int DO_TANH, int OUT_BF16>
__global__ __launch_bounds__(256) void aggregate3(const unsigned char* __restrict__ hs,
    const unsigned short* __restrict__ csr, const int* __restrict__ off,
    const float* __restrict__ dis, const float* __restrict__ bias,
    void* __restrict__ outp, int n) {
    __shared__ unsigned short eidx[ECAP];
    int t = threadIdx.x;
    int node0 = blockIdx.x * 4;
    int b0 = off[node0];
    int top = node0 + 4 < n ? node0 + 4 : n;
    int b4 = off[top];
    int mblk = b4 - b0;
    bool staged = (mblk <= ECAP);
    if (staged)
        for (int i = t; i < mblk; i += 256) eidx[i] = csr[b0 + i];
    __syncthreads();

    int node = node0 + (t >> 6);
    if (node >= n) return;
    int lane = t & 63;
    int half = lane >> 5;
    int fq = lane & 31;
    const unsigned* H = (const unsigned*)hs;   // 32 uints (128 fp8) per row

    int e0 = off[node];
    int e1 = off[node + 1];
    int le0 = e0 - b0;
    int m = e1 - e0;
    float ax = 0.f, ay = 0.f, az = 0.f, aw = 0.f;

    unsigned va[8], vb[8];
    auto sumB = [&](unsigned* v) {
#pragma unroll
        for (int j = 0; j < 8; ++j) {
            ax += __builtin_amdgcn_cvt_f32_fp8(v[j], 0);
            ay += __builtin_amdgcn_cvt_f32_fp8(v[j], 1);
            az += __builtin_amdgcn_cvt_f32_fp8(v[j], 2);
            aw += __builtin_amdgcn_cvt_f32_fp8(v[j], 3);
        }
    };
    auto loadL = [&](int i, unsigned* v) {
        int s[8];
#pragma unroll
        for (int j = 0; j < 8; ++j) s[j] = eidx[le0 + i + half + 2 * j];
#pragma unroll
        for (int j = 0; j < 8; ++j) v[j] = H[(size_t)s[j] * 32 + fq];
    };
    auto loadG = [&](int i, unsigned* v) {
        int s[8];
#pragma unroll
        for (int j = 0; j < 8; ++j) s[j] = csr[e0 + i + half + 2 * j];
#pragma unroll
        for (int j = 0; j < 8; ++j) v[j] = H[(size_t)s[j] * 32 + fq];
    };

    int nfull = m & ~15;
    if (staged) {
        if (nfull) {
            int B = nfull >> 4;
            loadL(0, va);
            int k = 1;
            for (; k + 1 < B; k += 2) {
                loadL(k << 4, vb);       sumB(va);
                loadL((k + 1) << 4, va); sumB(vb);
            }
            if (k < B) { loadL(k << 4, vb); sumB(va); sumB(vb); }
            else       { sumB(va); }
        }
        for (int e = nfull + half; e < m; e += 2) {
            unsigned v = H[(size_t)eidx[le0 + e] * 32 + fq];
            ax += __builtin_amdgcn_cvt_f32_fp8(v, 0);
            ay += __builtin_amdgcn_cvt_f32_fp8(v, 1);
            az += __builtin_amdgcn_cvt_f32_fp8(v, 2);
            aw += __builtin_amdgcn_cvt_f32_fp8(v, 3);
        }
    } else {
        if (nfull) {
            int B = nfull >> 4;
            loadG(0, va);
            int k = 1;
            for (; k + 1 < B; k += 2) {
                loadG(k << 4, vb);       sumB(va);
                loadG((k + 1) << 4, va); sumB(vb);
            }
            if (k < B) { loadG(k << 4, vb); sumB(va); sumB(vb); }
            else       { sumB(va); }
        }
        for (int e = nfull + half; e < m; e += 2) {
            unsigned v = H[(size_t)csr[e0 + e] * 32 + fq];
            ax += __builtin_amdgcn_cvt_f32_fp8(v, 0);
            ay += __builtin_amdgcn_cvt_f32_fp8(v, 1);
            az += __builtin_amdgcn_cvt_f32_fp8(v, 2);
            aw += __builtin_amdgcn_cvt_f32_fp8(v, 3);
        }
    }

    ax += __shfl_xor(ax, 32, 64);
    ay += __shfl_xor(ay, 32, 64);
    az += __shfl_xor(az, 32, 64);
    aw += __shfl_xor(aw, 32, 64);

    unsigned sv = H[(size_t)node * 32 + fq];   // self loop (row pre-scaled)
    ax += __builtin_amdgcn_cvt_f32_fp8(sv, 0);
    ay += __builtin_amdgcn_cvt_f32_fp8(sv, 1);
    az += __builtin_amdgcn_cvt_f32_fp8(sv, 2);
    aw += __builtin_amdgcn_cvt_f32_fp8(sv, 3);

    float dn = dis[node];
    float4 bv = ((const float4*)bias)[fq];
    float ox = fmaf(dn, ax, bv.x);
    float oy = fmaf(dn, ay, bv.y);
    float oz = fmaf(dn, az, bv.z);
    float ow = fmaf(dn, aw, bv.w);
    if (DO_TANH) {
        ox = tanhf(ox); oy = tanhf(oy); oz = tanhf(oz); ow = tanhf(ow);
    }
    if (half == 0) {
        if (OUT_BF16) {
            uint2 o;
            o.x = (unsigned)f2bf(ox) | ((unsigned)f2bf(oy) << 16);
            o.y = (unsigned)f2bf(oz) | ((unsigned)f2bf(ow) << 16);
            ((uint2*)outp)[(size_t)node * 32 + fq] = o;
        } else {
            float4 o = {ox, oy, oz, ow};
            *(float4*)((float*)outp + (size_t)node * 128 + fq * 4) = o;
        }
    }
}

// ---- fused pool + head: one block (64 threads) per graph ------------------
__global__ __launch_bounds__(64) void pool_head(const float* __restrict__ act,
    const int* __restrict__ batch, const float* __restrict__ Wout,
    const float* __restrict__ bout, float* __restrict__ out, int n, int C) {
    __shared__ float pooled[128];
    __shared__ float l[16];
    __shared__ float stats[2];
    int g = blockIdx.x;
    int t = threadIdx.x;
    int lo = 0, hi = n;
    while (lo < hi) { int mid = (lo + hi) >> 1; if (batch[mid] < g) lo = mid + 1; else hi = mid; }
    int lo1 = lo, hi1 = n;
    while (lo1 < hi1) { int mid = (lo1 + hi1) >> 1; if (batch[mid] < g + 1) lo1 = mid + 1; else hi1 = mid; }
    float ax = 0.f, ay = 0.f;
    for (int i = lo; i < lo1; ++i) {
        const float2 v = *(const float2*)(act + (size_t)i * 128 + t * 2);
        ax += v.x;
        ay += v.y;
    }
    int cnt = lo1 - lo;
    float inv = 1.0f / (float)(cnt > 0 ? cnt : 1);
    pooled[2 * t]     = ax * inv;
    pooled[2 * t + 1] = ay * inv;
    __syncthreads();
    if (t < C) {
        float acc = bout[t];
        for (int f = 0; f < 128; ++f)
            acc = fmaf(pooled[f], Wout[(size_t)f * C + t], acc);
        l[t] = acc;
    }
    __syncthreads();
    if (t == 0) {
        float m = -1e30f;
        for (int c = 0; c < C; ++c) m = fmaxf(m, l[c]);
        float s = 0.f;
        for (int c = 0; c < C; ++c) s += expf(l[c] - m);
        stats[0] = m;
        stats[1] = logf(s);
    }
    __syncthreads();
    if (t < C) out[(size_t)g * C + t] = l[t] - stats[0] - stats[1];
}

// ---------------------------------------------------------------------------
extern "C" void kernel_launch(void* const* d_in, const int* in_sizes, int n_in,
                              void* d_out, int out_size, void* d_ws, size_t ws_size,
                              hipStream_t stream) {
    const float* x     = (const float*)d_in[0];
    const int*   edge  = (const int*)d_in[1];
    const int*   batch = (const int*)d_in[2];
    const float* W0 = (const float*)d_in[3];
    const float* b0 = (const float*)d_in[4];
    const float* W1 = (const float*)d_in[5];
    const float* b1 = (const float*)d_in[6];
    const float* W2 = (const float*)d_in[7];
    const float* b2 = (const float*)d_in[8];
    const float* Wout = (const float*)d_in[9];
    const float* bout = (const float*)d_in[10];
    float* out = (float*)d_out;

    const int N = in_sizes[0] / 128;   // 50000 (< 65536 required for packing)
    const int E = in_sizes[1] / 2;     // 1600000
    const int C = in_sizes[10];        // 10
    const int G = out_size / C;        // 512

    const int* src = edge;
    const int* dst = edge + E;

    const int NBLK = (E + BLK_EDGES - 1) / BLK_EDGES;  // 391
    const int NB   = (N + 511) / 512;                  // 98 buckets
    const int NBQ  = NB * NBLK;                        // 38318 scan entries

    char* p = (char*)d_ws;
    auto alloc = [&](size_t bytes) -> void* {
        void* r = (void*)p;
        p += (bytes + 255) & ~(size_t)255;
        return r;
    };
    unsigned char* hs = (unsigned char*)alloc((size_t)N * 128);   // fp8 table
    float* act    = (float*)alloc((size_t)N * 128 * 4);  // bf16 x / bf16 act / fp32 act
    float* dis    = (float*)alloc((size_t)N * 4);
    int*   off    = (int*)alloc((size_t)(N + 1) * 4);
    int*   P      = (int*)alloc((size_t)(NBQ + 1) * 4);
    int*   bsum   = (int*)alloc(256 * 4);
    int*   boff   = (int*)alloc(256 * 4);
    unsigned* packed = (unsigned*)alloc((size_t)E * 4);
    unsigned short* csr16 = (unsigned short*)alloc((size_t)E * 2);
    unsigned short* wt0 = (unsigned short*)alloc(128 * 128 * 2);
    unsigned short* wt1 = (unsigned short*)alloc(128 * 128 * 2);
    unsigned short* wt2 = (unsigned short*)alloc(128 * 128 * 2);

    const int sb = (NBQ + 255) / 256;   // 150 (<=256 required by scan_top)

    // CSR build (no contended global atomics anywhere)
    blk_hist<<<NBLK, 256, 0, stream>>>(dst, P, E, NBLK, NB);
    scan_block<<<sb, 256, 0, stream>>>(P, P, bsum, NBQ);
    scan_top<<<1, 256, 0, stream>>>(bsum, boff, sb);
    scatter_packed<<<NBLK, 256, 0, stream>>>(src, dst, P, boff, packed, E, NBLK, NB);
    bucket_build<<<NB, 256, 0, stream>>>(packed, P, boff, off, dis, csr16, E, NBLK, N, NB);

    // weights -> bf16 transposed + x -> bf16 (into act), single launch
    unsigned short* actb = (unsigned short*)act;
    const int n4 = N * 32;
    prep<<<(3 * 16384 + n4 + 255) / 256, 256, 0, stream>>>(W0, W1, W2, wt0, wt1, wt2,
                                                           x, actb, n4);

    const int gb = (N + 63) / 64;    // 782 blocks of 128 threads
    const int ab = (N + 3) / 4;

    gemm_mfma<<<gb, 128, 0, stream>>>(actb, wt0, dis, hs, N);
    aggregate3<1, 1><<<ab, 256, 0, stream>>>(hs, csr16, off, dis, b0, act, N);
    gemm_mfma<<<gb, 128, 0, stream>>>(actb, wt1, dis, hs, N);
    aggregate3<1, 1><<<ab, 256, 0, stream>>>(hs, csr16, off, dis, b1, act, N);
    gemm_mfma<<<gb, 128, 0, stream>>>(actb, wt2, dis, hs, N);
    aggregate3<0, 0><<<ab, 256, 0, stream>>>(hs, csr16, off, dis, b2, act, N);

    pool_head<<<G, 64, 0, stream>>>(act, batch, Wout, bout, out, N, C);
}

// Round 13
// 335.677 us; speedup vs baseline: 1.6184x; 1.0757x over previous
//
#include <hip/hip_runtime.h>
#include <math.h>

// ---------------------------------------------------------------------------
// GCN: 3x (MFMA GEMM(+dis scale, fp8 table out) -> pull-aggregate -> tanh)
//      -> fused pool+head
// R13: pool_head parallelized — R12 profile showed it at 47us with 2 waves/CU
//      (512x64 launch, serial ~97-node walk = pure latency). Now 256 thr/graph:
//      4 waves strip-mine the node range, LDS partial sums, wave 0 reduces +
//      head. Everything else identical to R12.
// ---------------------------------------------------------------------------

#define BLK_EDGES 4096
#define MAXB 128          // max dst-buckets for CSR build (N<=65536)
#define ECAP 2048         // LDS edge-index capacity per aggregate block
#define WS_STRIDE 136     // LDS row stride for W^T (elements; 272B, 16B-aligned)

typedef __attribute__((ext_vector_type(8))) short bf16x8;
typedef __attribute__((ext_vector_type(4))) float f32x4;

static __device__ inline unsigned short f2bf(float f) {
    unsigned u = __float_as_uint(f);
    unsigned r = (u + 0x7FFFu + ((u >> 16) & 1u)) >> 16;   // RNE
    return (unsigned short)r;
}
static __device__ inline float bf_lo(unsigned u) { return __uint_as_float(u << 16); }
static __device__ inline float bf_hi(unsigned u) { return __uint_as_float(u & 0xFFFF0000u); }
static __device__ inline unsigned char f2fp8(float v) {
    v = fminf(fmaxf(v, -240.f), 240.f);                    // avoid e4m3 NaN
    int u = __builtin_amdgcn_cvt_pk_fp8_f32(v, v, 0, false);
    return (unsigned char)(u & 0xFF);
}

// ---- per-block bucket histogram (bucket = dst >> 9), transposed output ----
__global__ __launch_bounds__(256) void blk_hist(const int* __restrict__ dst,
        int* __restrict__ histT, int E, int NBLK, int NB) {
    __shared__ int h[MAXB];
    int blk = blockIdx.x, t = threadIdx.x;
    for (int i = t; i < NB; i += 256) h[i] = 0;
    __syncthreads();
    int lo = blk * BLK_EDGES;
    int hi = min(E, lo + BLK_EDGES);
    for (int i = lo + t; i < hi; i += 256)
        atomicAdd(&h[dst[i] >> 9], 1);
    __syncthreads();
    for (int i = t; i < NB; i += 256) histT[i * NBLK + blk] = h[i];
}

// ---- 2-kernel scan (per-chunk exclusive + chunk offsets; consumers fold) --
__global__ void scan_block(const int* __restrict__ cnt, int* __restrict__ off,
                           int* __restrict__ bsum, int n) {
    __shared__ int lds[256];
    int t = threadIdx.x;
    int i = blockIdx.x * 256 + t;
    int v = (i < n) ? cnt[i] : 0;
    lds[t] = v;
    __syncthreads();
    for (int d = 1; d < 256; d <<= 1) {
        int add = (t >= d) ? lds[t - d] : 0;
        __syncthreads();
        lds[t] += add;
        __syncthreads();
    }
    if (i < n) off[i] = lds[t] - v;      // exclusive within 256-chunk
    if (t == 255) bsum[blockIdx.x] = lds[255];
}

__global__ void scan_top(const int* __restrict__ bsum, int* __restrict__ boff,
                         int nblocks) {
    __shared__ int lds[256];
    int t = threadIdx.x;
    int v = (t < nblocks) ? bsum[t] : 0;
    lds[t] = v;
    __syncthreads();
    for (int d = 1; d < 256; d <<= 1) {
        int add = (t >= d) ? lds[t - d] : 0;
        __syncthreads();
        lds[t] += add;
        __syncthreads();
    }
    if (t < nblocks) boff[t] = lds[t] - v;   // exclusive chunk offsets
}

// ---- scatter packed edges into private (block,bucket) runs ----------------
__global__ __launch_bounds__(256) void scatter_packed(const int* __restrict__ src,
        const int* __restrict__ dst, const int* __restrict__ P,
        const int* __restrict__ boff, unsigned* __restrict__ packed,
        int E, int NBLK, int NB) {
    __shared__ int cur[MAXB];
    int blk = blockIdx.x, t = threadIdx.x;
    for (int i = t; i < NB; i += 256) {
        int idx = i * NBLK + blk;
        cur[i] = P[idx] + boff[idx >> 8];
    }
    __syncthreads();
    int lo = blk * BLK_EDGES;
    int hi = min(E, lo + BLK_EDGES);
    for (int i = lo + t; i < hi; i += 256) {
        int d = dst[i];
        int pos = atomicAdd(&cur[d >> 9], 1);   // LDS atomic, block-local
        packed[pos] = ((unsigned)d << 16) | (unsigned)src[i];
    }
}

// ---- per-bucket: node counts, local scan -> off/dis, fill ushort CSR ------
__global__ __launch_bounds__(256) void bucket_build(const unsigned* __restrict__ packed,
        const int* __restrict__ P, const int* __restrict__ boff, int* __restrict__ off,
        float* __restrict__ dis, unsigned short* __restrict__ csr16,
        int E, int NBLK, int N, int NB) {
    __shared__ int cnt[512];
    __shared__ int loc[512];
    __shared__ int ps[256];
    int b = blockIdx.x, t = threadIdx.x;
    int i0 = b * NBLK, i1 = (b + 1) * NBLK;
    int start = P[i0] + boff[i0 >> 8];
    int end   = (b == NB - 1) ? E : (P[i1] + boff[i1 >> 8]);
    cnt[t] = 0; cnt[t + 256] = 0;
    __syncthreads();
    for (int i = start + t; i < end; i += 256)
        atomicAdd(&cnt[(packed[i] >> 16) & 511], 1);
    __syncthreads();
    int c0 = cnt[2 * t], c1 = cnt[2 * t + 1];
    ps[t] = c0 + c1;
    __syncthreads();
    for (int d = 1; d < 256; d <<= 1) {
        int add = (t >= d) ? ps[t - d] : 0;
        __syncthreads();
        ps[t] += add;
        __syncthreads();
    }
    int pexcl = ps[t] - (c0 + c1);
    loc[2 * t]     = start + pexcl;
    loc[2 * t + 1] = start + pexcl + c0;
    __syncthreads();
    int node0 = b * 512;
    for (int l = t; l < 512; l += 256) {
        int node = node0 + l;
        if (node < N) {
            off[node] = loc[l];
            dis[node] = rsqrtf((float)cnt[l] + 1.0f);
        }
    }
    if (b == NB - 1 && t == 0) off[N] = E;
    __syncthreads();
    for (int i = start + t; i < end; i += 256) {
        unsigned p = packed[i];
        int l = (p >> 16) & 511;
        int pos = atomicAdd(&loc[l], 1);
        csr16[pos] = (unsigned short)(p & 0xFFFFu);
    }
}

// ---- prep: 3x W transpose->bf16 + x->bf16, one launch ---------------------
__global__ __launch_bounds__(256) void prep(const float* __restrict__ W0,
        const float* __restrict__ W1, const float* __restrict__ W2,
        unsigned short* __restrict__ wt0, unsigned short* __restrict__ wt1,
        unsigned short* __restrict__ wt2, const float* __restrict__ x,
        unsigned short* __restrict__ xb, int n4) {
    int i = blockIdx.x * 256 + threadIdx.x;
    if (i < 3 * 16384) {
        int w = i >> 14, j = i & 16383;
        int k = j >> 7, n2 = j & 127;
        const float* Wp = (w == 0) ? W0 : (w == 1) ? W1 : W2;
        unsigned short* Wt = (w == 0) ? wt0 : (w == 1) ? wt1 : wt2;
        Wt[n2 * 128 + k] = f2bf(Wp[k * 128 + n2]);
    } else {
        int j = i - 3 * 16384;
        if (j < n4) {
            float4 f = ((const float4*)x)[j];
            ushort4 o = {f2bf(f.x), f2bf(f.y), f2bf(f.z), f2bf(f.w)};
            ((ushort4*)xb)[j] = o;
        }
    }
}

// ---- MFMA GEMM: Hs8[r] = fp8( dis[r] * (A16[r] @ W) ) ---------------------
__global__ __launch_bounds__(128) void gemm_mfma(const unsigned short* __restrict__ A16,
        const unsigned short* __restrict__ Wt, const float* __restrict__ dis,
        unsigned char* __restrict__ Hs8, int n) {
    __shared__ unsigned short Ws[128 * WS_STRIDE];   // 34.8 KB
    int t = threadIdx.x;
    for (int i = t; i < 128 * 16; i += 128) {
        int r = i >> 4, j = i & 15;
        uint4 u = ((const uint4*)(Wt + r * 128))[j];
        *(uint4*)&Ws[r * WS_STRIDE + j * 8] = u;
    }
    __syncthreads();

    int wave = t >> 6, lane = t & 63;
    int quad = lane >> 4, l16 = lane & 15;
    int row0 = blockIdx.x * 64 + wave * 32;

    int ra0 = row0 + l16;      if (ra0 >= n) ra0 = n - 1;
    int ra1 = row0 + 16 + l16; if (ra1 >= n) ra1 = n - 1;

    f32x4 acc[2][8];
    const f32x4 z = {0.f, 0.f, 0.f, 0.f};
#pragma unroll
    for (int mi = 0; mi < 2; ++mi)
#pragma unroll
        for (int ni = 0; ni < 8; ++ni) acc[mi][ni] = z;

#pragma unroll
    for (int ks = 0; ks < 4; ++ks) {
        int kof = ks * 32 + quad * 8;
        bf16x8 a0 = *(const bf16x8*)(A16 + (size_t)ra0 * 128 + kof);
        bf16x8 a1 = *(const bf16x8*)(A16 + (size_t)ra1 * 128 + kof);
        bf16x8 b[8];
#pragma unroll
        for (int ni = 0; ni < 8; ++ni)
            b[ni] = *(const bf16x8*)&Ws[(ni * 16 + l16) * WS_STRIDE + kof];
#pragma unroll
        for (int ni = 0; ni < 8; ++ni) {
            acc[0][ni] = __builtin_amdgcn_mfma_f32_16x16x32_bf16(a0, b[ni], acc[0][ni], 0, 0, 0);
            acc[1][ni] = __builtin_amdgcn_mfma_f32_16x16x32_bf16(a1, b[ni], acc[1][ni], 0, 0, 0);
        }
    }
#pragma unroll
    for (int mi = 0; mi < 2; ++mi) {
        int rb = row0 + mi * 16 + quad * 4;
#pragma unroll
        for (int reg = 0; reg < 4; ++reg) {
            int r = rb + reg;
            if (r < n) {
                float dv = dis[r];
#pragma unroll
                for (int ni = 0; ni < 8; ++ni)
                    Hs8[(size_t)r * 128 + ni * 16 + l16] = f2fp8(acc[mi][ni][reg] * dv);
            }
        }
    }
}

// ---- pull aggregation over fp8 table: LDS indices + dbuf gathers ----------
template<int DO_TANH, int OUT_BF16>
__global__ __launch_bounds__(256) void aggregate3(const unsigned char* __restrict__ hs,
    const unsigned short* __restrict__ csr, const int* __restrict__ off,
    const float* __restrict__ dis, const float* __restrict__ bias,
    void* __restrict__ outp, int n) {
    __shared__ unsigned short eidx[ECAP];
    int t = threadIdx.x;
    int node0 = blockIdx.x * 4;
    int b0 = off[node0];
    int top = node0 + 4 < n ? node0 + 4 : n;
    int b4 = off[top];
    int mblk = b4 - b0;
    bool staged = (mblk <= ECAP);
    if (staged)
        for (int i = t; i < mblk; i += 256) eidx[i] = csr[b0 + i];
    __syncthreads();

    int node = node0 + (t >> 6);
    if (node >= n) return;
    int lane = t & 63;
    int half = lane >> 5;
    int fq = lane & 31;
    const unsigned* H = (const unsigned*)hs;   // 32 uints (128 fp8) per row

    int e0 = off[node];
    int e1 = off[node + 1];
    int le0 = e0 - b0;
    int m = e1 - e0;
    float ax = 0.f, ay = 0.f, az = 0.f, aw = 0.f;

    unsigned va[8], vb[8];
    auto sumB = [&](unsigned* v) {
#pragma unroll
        for (int j = 0; j < 8; ++j) {
            ax += __builtin_amdgcn_cvt_f32_fp8(v[j], 0);
            ay += __builtin_amdgcn_cvt_f32_fp8(v[j], 1);
            az += __builtin_amdgcn_cvt_f32_fp8(v[j], 2);
            aw += __builtin_amdgcn_cvt_f32_fp8(v[j], 3);
        }
    };
    auto loadL = [&](int i, unsigned* v) {
        int s[8];
#pragma unroll
        for (int j = 0; j < 8; ++j) s[j] = eidx[le0 + i + half + 2 * j];
#pragma unroll
        for (int j = 0; j < 8; ++j) v[j] = H[(size_t)s[j] * 32 + fq];
    };
    auto loadG = [&](int i, unsigned* v) {
        int s[8];
#pragma unroll
        for (int j = 0; j < 8; ++j) s[j] = csr[e0 + i + half + 2 * j];
#pragma unroll
        for (int j = 0; j < 8; ++j) v[j] = H[(size_t)s[j] * 32 + fq];
    };

    int nfull = m & ~15;
    if (staged) {
        if (nfull) {
            int B = nfull >> 4;
            loadL(0, va);
            int k = 1;
            for (; k + 1 < B; k += 2) {
                loadL(k << 4, vb);       sumB(va);
                loadL((k + 1) << 4, va); sumB(vb);
            }
            if (k < B) { loadL(k << 4, vb); sumB(va); sumB(vb); }
            else       { sumB(va); }
        }
        for (int e = nfull + half; e < m; e += 2) {
            unsigned v = H[(size_t)eidx[le0 + e] * 32 + fq];
            ax += __builtin_amdgcn_cvt_f32_fp8(v, 0);
            ay += __builtin_amdgcn_cvt_f32_fp8(v, 1);
            az += __builtin_amdgcn_cvt_f32_fp8(v, 2);
            aw += __builtin_amdgcn_cvt_f32_fp8(v, 3);
        }
    } else {
        if (nfull) {
            int B = nfull >> 4;
            loadG(0, va);
            int k = 1;
            for (; k + 1 < B; k += 2) {
                loadG(k << 4, vb);       sumB(va);
                loadG((k + 1) << 4, va); sumB(vb);
            }
            if (k < B) { loadG(k << 4, vb); sumB(va); sumB(vb); }
            else       { sumB(va); }
        }
        for (int e = nfull + half; e < m; e += 2) {
            unsigned v = H[(size_t)csr[e0 + e] * 32 + fq];
            ax += __builtin_amdgcn_cvt_f32_fp8(v, 0);
            ay += __builtin_amdgcn_cvt_f32_fp8(v, 1);
            az += __builtin_amdgcn_cvt_f32_fp8(v, 2);
            aw += __builtin_amdgcn_cvt_f32_fp8(v, 3);
        }
    }

    ax += __shfl_xor(ax, 32, 64);
    ay += __shfl_xor(ay, 32, 64);
    az += __shfl_xor(az, 32, 64);
    aw += __shfl_xor(aw, 32, 64);

    unsigned sv = H[(size_t)node * 32 + fq];   // self loop (row pre-scaled)
    ax += __builtin_amdgcn_cvt_f32_fp8(sv, 0);
    ay += __builtin_amdgcn_cvt_f32_fp8(sv, 1);
    az += __builtin_amdgcn_cvt_f32_fp8(sv, 2);
    aw += __builtin_amdgcn_cvt_f32_fp8(sv, 3);

    float dn = dis[node];
    float4 bv = ((const float4*)bias)[fq];
    float ox = fmaf(dn, ax, bv.x);
    float oy = fmaf(dn, ay, bv.y);
    float oz = fmaf(dn, az, bv.z);
    float ow = fmaf(dn, aw, bv.w);
    if (DO_TANH) {
        ox = tanhf(ox); oy = tanhf(oy); oz = tanhf(oz); ow = tanhf(ow);
    }
    if (half == 0) {
        if (OUT_BF16) {
            uint2 o;
            o.x = (unsigned)f2bf(ox) | ((unsigned)f2bf(oy) << 16);
            o.y = (unsigned)f2bf(oz) | ((unsigned)f2bf(ow) << 16);
            ((uint2*)outp)[(size_t)node * 32 + fq] = o;
        } else {
            float4 o = {ox, oy, oz, ow};
            *(float4*)((float*)outp + (size_t)node * 128 + fq * 4) = o;
        }
    }
}

// ---- fused pool + head: 256 threads (4 waves) per graph -------------------
// Wave w sums node strip lo+w, lo+w+4, ... into psum[w]; wave 0 reduces,
// computes logits + log_softmax. 4x waves of R12's version (latency-bound).
__global__ __launch_bounds__(256) void pool_head(const float* __restrict__ act,
    const int* __restrict__ batch, const float* __restrict__ Wout,
    const float* __restrict__ bout, float* __restrict__ out, int n, int C) {
    __shared__ float psum[4][128];
    __shared__ float l[16];
    __shared__ float stats[2];
    int g = blockIdx.x;
    int t = threadIdx.x;
    int w = t >> 6;
    int lane = t & 63;
    // bounds via binary search on sorted batch
    int lo = 0, hi = n;
    while (lo < hi) { int mid = (lo + hi) >> 1; if (batch[mid] < g) lo = mid + 1; else hi = mid; }
    int lo1 = lo, hi1 = n;
    while (lo1 < hi1) { int mid = (lo1 + hi1) >> 1; if (batch[mid] < g + 1) lo1 = mid + 1; else hi1 = mid; }
    float ax = 0.f, ay = 0.f;
    for (int i = lo + w; i < lo1; i += 4) {
        const float2 v = *(const float2*)(act + (size_t)i * 128 + lane * 2);
        ax += v.x;
        ay += v.y;
    }
    psum[w][2 * lane]     = ax;
    psum[w][2 * lane + 1] = ay;
    __syncthreads();
    if (w == 0) {
        int cnt = lo1 - lo;
        float inv = 1.0f / (float)(cnt > 0 ? cnt : 1);
        float sx = (psum[0][2 * lane] + psum[1][2 * lane])
                 + (psum[2][2 * lane] + psum[3][2 * lane]);
        float sy = (psum[0][2 * lane + 1] + psum[1][2 * lane + 1])
                 + (psum[2][2 * lane + 1] + psum[3][2 * lane + 1]);
        psum[0][2 * lane]     = sx * inv;   // reuse psum[0] as pooled
        psum[0][2 * lane + 1] = sy * inv;
    }
    __syncthreads();
    if (t < C) {
        float acc = bout[t];
        for (int f = 0; f < 128; ++f)
            acc = fmaf(psum[0][f], Wout[(size_t)f * C + t], acc);
        l[t] = acc;
    }
    __syncthreads();
    if (t == 0) {
        float m = -1e30f;
        for (int c = 0; c < C; ++c) m = fmaxf(m, l[c]);
        float s = 0.f;
        for (int c = 0; c < C; ++c) s += expf(l[c] - m);
        stats[0] = m;
        stats[1] = logf(s);
    }
    __syncthreads();
    if (t < C) out[(size_t)g * C + t] = l[t] - stats[0] - stats[1];
}

// ---------------------------------------------------------------------------
extern "C" void kernel_launch(void* const* d_in, const int* in_sizes, int n_in,
                              void* d_out, int out_size, void* d_ws, size_t ws_size,
                              hipStream_t stream) {
    const float* x     = (const float*)d_in[0];
    const int*   edge  = (const int*)d_in[1];
    const int*   batch = (const int*)d_in[2];
    const float* W0 = (const float*)d_in[3];
    const float* b0 = (const float*)d_in[4];
    const float* W1 = (const float*)d_in[5];
    const float* b1 = (const float*)d_in[6];
    const float* W2 = (const float*)d_in[7];
    const float* b2 = (const float*)d_in[8];
    const float* Wout = (const float*)d_in[9];
    const float* bout = (const float*)d_in[10];
    float* out = (float*)d_out;

    const int N = in_sizes[0] / 128;   // 50000 (< 65536 required for packing)
    const int E = in_sizes[1] / 2;     // 1600000
    const int C = in_sizes[10];        // 10
    const int G = out_size / C;        // 512

    const int* src = edge;
    const int* dst = edge + E;

    const int NBLK = (E + BLK_EDGES - 1) / BLK_EDGES;  // 391
    const int NB   = (N + 511) / 512;                  // 98 buckets
    const int NBQ  = NB * NBLK;                        // 38318 scan entries

    char* p = (char*)d_ws;
    auto alloc = [&](size_t bytes) -> void* {
        void* r = (void*)p;
        p += (bytes + 255) & ~(size_t)255;
        return r;
    };
    unsigned char* hs = (unsigned char*)alloc((size_t)N * 128);   // fp8 table
    float* act    = (float*)alloc((size_t)N * 128 * 4);  // bf16 x / bf16 act / fp32 act
    float* dis    = (float*)alloc((size_t)N * 4);
    int*   off    = (int*)alloc((size_t)(N + 1) * 4);
    int*   P      = (int*)alloc((size_t)(NBQ + 1) * 4);
    int*   bsum   = (int*)alloc(256 * 4);
    int*   boff   = (int*)alloc(256 * 4);
    unsigned* packed = (unsigned*)alloc((size_t)E * 4);
    unsigned short* csr16 = (unsigned short*)alloc((size_t)E * 2);
    unsigned short* wt0 = (unsigned short*)alloc(128 * 128 * 2);
    unsigned short* wt1 = (unsigned short*)alloc(128 * 128 * 2);
    unsigned short* wt2 = (unsigned short*)alloc(128 * 128 * 2);

    const int sb = (NBQ + 255) / 256;   // 150 (<=256 required by scan_top)

    // CSR build (no contended global atomics anywhere)
    blk_hist<<<NBLK, 256, 0, stream>>>(dst, P, E, NBLK, NB);
    scan_block<<<sb, 256, 0, stream>>>(P, P, bsum, NBQ);
    scan_top<<<1, 256, 0, stream>>>(bsum, boff, sb);
    scatter_packed<<<NBLK, 256, 0, stream>>>(src, dst, P, boff, packed, E, NBLK, NB);
    bucket_build<<<NB, 256, 0, stream>>>(packed, P, boff, off, dis, csr16, E, NBLK, N, NB);

    // weights -> bf16 transposed + x -> bf16 (into act), single launch
    unsigned short* actb = (unsigned short*)act;
    const int n4 = N * 32;
    prep<<<(3 * 16384 + n4 + 255) / 256, 256, 0, stream>>>(W0, W1, W2, wt0, wt1, wt2,
                                                           x, actb, n4);

    const int gb = (N + 63) / 64;    // 782 blocks of 128 threads
    const int ab = (N + 3) / 4;

    gemm_mfma<<<gb, 128, 0, stream>>>(actb, wt0, dis, hs, N);
    aggregate3<1, 1><<<ab, 256, 0, stream>>>(hs, csr16, off, dis, b0, act, N);
    gemm_mfma<<<gb, 128, 0, stream>>>(actb, wt1, dis, hs, N);
    aggregate3<1, 1><<<ab, 256, 0, stream>>>(hs, csr16, off, dis, b1, act, N);
    gemm_mfma<<<gb, 128, 0, stream>>>(actb, wt2, dis, hs, N);
    aggregate3<0, 0><<<ab, 256, 0, stream>>>(hs, csr16, off, dis, b2, act, N);

    pool_head<<<G, 256, 0, stream>>>(act, batch, Wout, bout, out, N, C);
}

// Round 14
// 331.677 us; speedup vs baseline: 1.6380x; 1.0121x over previous
//
#include <hip/hip_runtime.h>
#include <math.h>

// ---------------------------------------------------------------------------
// GCN: 3x (MFMA GEMM(+dis scale, fp8 table out) -> pull-aggregate -> tanh)
//      -> fused pool+head
// R14: consolidation — tobf16 deleted (GEMM0 reads fp32 x via IN_F32 path),
//      weight-prep merged into blk_hist launch, final act is bf16 (halves
//      last-aggregate write + pool read). Hot kernels otherwise identical.
// ---------------------------------------------------------------------------

#define BLK_EDGES 4096
#define MAXB 128          // max dst-buckets for CSR build (N<=65536)
#define ECAP 2048         // LDS edge-index capacity per aggregate block
#define WS_STRIDE 136     // LDS row stride for W^T (elements; 272B, 16B-aligned)

typedef __attribute__((ext_vector_type(8))) short bf16x8;
typedef __attribute__((ext_vector_type(4))) float f32x4;

static __device__ inline unsigned short f2bf(float f) {
    unsigned u = __float_as_uint(f);
    unsigned r = (u + 0x7FFFu + ((u >> 16) & 1u)) >> 16;   // RNE
    return (unsigned short)r;
}
static __device__ inline float bf_lo(unsigned u) { return __uint_as_float(u << 16); }
static __device__ inline float bf_hi(unsigned u) { return __uint_as_float(u & 0xFFFF0000u); }
static __device__ inline unsigned char f2fp8(float v) {
    v = fminf(fmaxf(v, -240.f), 240.f);                    // avoid e4m3 NaN
    int u = __builtin_amdgcn_cvt_pk_fp8_f32(v, v, 0, false);
    return (unsigned char)(u & 0xFF);
}

// ---- bucket histogram (blocks < NBLK) + weight transpose (blocks >= NBLK) -
__global__ __launch_bounds__(256) void blk_hist_prep(const int* __restrict__ dst,
        int* __restrict__ histT, int E, int NBLK, int NB,
        const float* __restrict__ W0, const float* __restrict__ W1,
        const float* __restrict__ W2, unsigned short* __restrict__ wt0,
        unsigned short* __restrict__ wt1, unsigned short* __restrict__ wt2) {
    __shared__ int h[MAXB];
    int blk = blockIdx.x, t = threadIdx.x;
    if (blk >= NBLK) {
        int i = (blk - NBLK) * 256 + t;       // covers 3*16384 exactly (192 blocks)
        int w = i >> 14, j = i & 16383;
        int k = j >> 7, n2 = j & 127;
        const float* Wp = (w == 0) ? W0 : (w == 1) ? W1 : W2;
        unsigned short* Wt = (w == 0) ? wt0 : (w == 1) ? wt1 : wt2;
        Wt[n2 * 128 + k] = f2bf(Wp[k * 128 + n2]);
        return;
    }
    for (int i = t; i < NB; i += 256) h[i] = 0;
    __syncthreads();
    int lo = blk * BLK_EDGES;
    int hi = min(E, lo + BLK_EDGES);
    for (int i = lo + t; i < hi; i += 256)
        atomicAdd(&h[dst[i] >> 9], 1);
    __syncthreads();
    for (int i = t; i < NB; i += 256) histT[i * NBLK + blk] = h[i];
}

// ---- 2-kernel scan (per-chunk exclusive + chunk offsets; consumers fold) --
__global__ void scan_block(const int* __restrict__ cnt, int* __restrict__ off,
                           int* __restrict__ bsum, int n) {
    __shared__ int lds[256];
    int t = threadIdx.x;
    int i = blockIdx.x * 256 + t;
    int v = (i < n) ? cnt[i] : 0;
    lds[t] = v;
    __syncthreads();
    for (int d = 1; d < 256; d <<= 1) {
        int add = (t >= d) ? lds[t - d] : 0;
        __syncthreads();
        lds[t] += add;
        __syncthreads();
    }
    if (i < n) off[i] = lds[t] - v;      // exclusive within 256-chunk
    if (t == 255) bsum[blockIdx.x] = lds[255];
}

__global__ void scan_top(const int* __restrict__ bsum, int* __restrict__ boff,
                         int nblocks) {
    __shared__ int lds[256];
    int t = threadIdx.x;
    int v = (t < nblocks) ? bsum[t] : 0;
    lds[t] = v;
    __syncthreads();
    for (int d = 1; d < 256; d <<= 1) {
        int add = (t >= d) ? lds[t - d] : 0;
        __syncthreads();
        lds[t] += add;
        __syncthreads();
    }
    if (t < nblocks) boff[t] = lds[t] - v;   // exclusive chunk offsets
}

// ---- scatter packed edges into private (block,bucket) runs ----------------
__global__ __launch_bounds__(256) void scatter_packed(const int* __restrict__ src,
        const int* __restrict__ dst, const int* __restrict__ P,
        const int* __restrict__ boff, unsigned* __restrict__ packed,
        int E, int NBLK, int NB) {
    __shared__ int cur[MAXB];
    int blk = blockIdx.x, t = threadIdx.x;
    for (int i = t; i < NB; i += 256) {
        int idx = i * NBLK + blk;
        cur[i] = P[idx] + boff[idx >> 8];
    }
    __syncthreads();
    int lo = blk * BLK_EDGES;
    int hi = min(E, lo + BLK_EDGES);
    for (int i = lo + t; i < hi; i += 256) {
        int d = dst[i];
        int pos = atomicAdd(&cur[d >> 9], 1);   // LDS atomic, block-local
        packed[pos] = ((unsigned)d << 16) | (unsigned)src[i];
    }
}

// ---- per-bucket: node counts, local scan -> off/dis, fill ushort CSR ------
__global__ __launch_bounds__(256) void bucket_build(const unsigned* __restrict__ packed,
        const int* __restrict__ P, const int* __restrict__ boff, int* __restrict__ off,
        float* __restrict__ dis, unsigned short* __restrict__ csr16,
        int E, int NBLK, int N, int NB) {
    __shared__ int cnt[512];
    __shared__ int loc[512];
    __shared__ int ps[256];
    int b = blockIdx.x, t = threadIdx.x;
    int i0 = b * NBLK, i1 = (b + 1) * NBLK;
    int start = P[i0] + boff[i0 >> 8];
    int end   = (b == NB - 1) ? E : (P[i1] + boff[i1 >> 8]);
    cnt[t] = 0; cnt[t + 256] = 0;
    __syncthreads();
    for (int i = start + t; i < end; i += 256)
        atomicAdd(&cnt[(packed[i] >> 16) & 511], 1);
    __syncthreads();
    int c0 = cnt[2 * t], c1 = cnt[2 * t + 1];
    ps[t] = c0 + c1;
    __syncthreads();
    for (int d = 1; d < 256; d <<= 1) {
        int add = (t >= d) ? ps[t - d] : 0;
        __syncthreads();
        ps[t] += add;
        __syncthreads();
    }
    int pexcl = ps[t] - (c0 + c1);
    loc[2 * t]     = start + pexcl;
    loc[2 * t + 1] = start + pexcl + c0;
    __syncthreads();
    int node0 = b * 512;
    for (int l = t; l < 512; l += 256) {
        int node = node0 + l;
        if (node < N) {
            off[node] = loc[l];
            dis[node] = rsqrtf((float)cnt[l] + 1.0f);
        }
    }
    if (b == NB - 1 && t == 0) off[N] = E;
    __syncthreads();
    for (int i = start + t; i < end; i += 256) {
        unsigned p = packed[i];
        int l = (p >> 16) & 511;
        int pos = atomicAdd(&loc[l], 1);
        csr16[pos] = (unsigned short)(p & 0xFFFFu);
    }
}

// ---- MFMA GEMM: Hs8[r] = fp8( dis[r] * (A[r] @ W) ) -----------------------
// A: fp32 [n][128] (IN_F32=1, layer 0) or bf16 [n][128] (layers 1/2).
// Wt bf16 [128 out][128 in] staged in LDS. 128 threads = 2 waves, 64 rows/blk.
// Layouts: A[m=lane&15][k=quad*8+j], B[n=lane&15][k=quad*8+j],
// C/D[row=quad*4+reg][col=lane&15]. Output fp8 e4m3 table (128 B/row).
template<int IN_F32>
__global__ __launch_bounds__(128) void gemm_mfma(const void* __restrict__ Av,
        const unsigned short* __restrict__ Wt, const float* __restrict__ dis,
        unsigned char* __restrict__ Hs8, int n) {
    __shared__ unsigned short Ws[128 * WS_STRIDE];   // 34.8 KB
    int t = threadIdx.x;
    for (int i = t; i < 128 * 16; i += 128) {
        int r = i >> 4, j = i & 15;
        uint4 u = ((const uint4*)(Wt + r * 128))[j];
        *(uint4*)&Ws[r * WS_STRIDE + j * 8] = u;
    }
    __syncthreads();

    int wave = t >> 6, lane = t & 63;
    int quad = lane >> 4, l16 = lane & 15;
    int row0 = blockIdx.x * 64 + wave * 32;

    int ra0 = row0 + l16;      if (ra0 >= n) ra0 = n - 1;
    int ra1 = row0 + 16 + l16; if (ra1 >= n) ra1 = n - 1;

    f32x4 acc[2][8];
    const f32x4 z = {0.f, 0.f, 0.f, 0.f};
#pragma unroll
    for (int mi = 0; mi < 2; ++mi)
#pragma unroll
        for (int ni = 0; ni < 8; ++ni) acc[mi][ni] = z;

#pragma unroll
    for (int ks = 0; ks < 4; ++ks) {
        int kof = ks * 32 + quad * 8;
        bf16x8 a0, a1;
        if (IN_F32) {
            const float* A0 = (const float*)Av + (size_t)ra0 * 128 + kof;
            const float* A1 = (const float*)Av + (size_t)ra1 * 128 + kof;
            float4 p0 = ((const float4*)A0)[0], p1 = ((const float4*)A0)[1];
            float4 q0 = ((const float4*)A1)[0], q1 = ((const float4*)A1)[1];
            a0[0] = (short)f2bf(p0.x); a0[1] = (short)f2bf(p0.y);
            a0[2] = (short)f2bf(p0.z); a0[3] = (short)f2bf(p0.w);
            a0[4] = (short)f2bf(p1.x); a0[5] = (short)f2bf(p1.y);
            a0[6] = (short)f2bf(p1.z); a0[7] = (short)f2bf(p1.w);
            a1[0] = (short)f2bf(q0.x); a1[1] = (short)f2bf(q0.y);
            a1[2] = (short)f2bf(q0.z); a1[3] = (short)f2bf(q0.w);
            a1[4] = (short)f2bf(q1.x); a1[5] = (short)f2bf(q1.y);
            a1[6] = (short)f2bf(q1.z); a1[7] = (short)f2bf(q1.w);
        } else {
            a0 = *(const bf16x8*)((const unsigned short*)Av + (size_t)ra0 * 128 + kof);
            a1 = *(const bf16x8*)((const unsigned short*)Av + (size_t)ra1 * 128 + kof);
        }
        bf16x8 b[8];
#pragma unroll
        for (int ni = 0; ni < 8; ++ni)
            b[ni] = *(const bf16x8*)&Ws[(ni * 16 + l16) * WS_STRIDE + kof];
#pragma unroll
        for (int ni = 0; ni < 8; ++ni) {
            acc[0][ni] = __builtin_amdgcn_mfma_f32_16x16x32_bf16(a0, b[ni], acc[0][ni], 0, 0, 0);
            acc[1][ni] = __builtin_amdgcn_mfma_f32_16x16x32_bf16(a1, b[ni], acc[1][ni], 0, 0, 0);
        }
    }
#pragma unroll
    for (int mi = 0; mi < 2; ++mi) {
        int rb = row0 + mi * 16 + quad * 4;
#pragma unroll
        for (int reg = 0; reg < 4; ++reg) {
            int r = rb + reg;
            if (r < n) {
                float dv = dis[r];
#pragma unroll
                for (int ni = 0; ni < 8; ++ni)
                    Hs8[(size_t)r * 128 + ni * 16 + l16] = f2fp8(acc[mi][ni][reg] * dv);
            }
        }
    }
}

// ---- pull aggregation over fp8 table: LDS indices + dbuf gathers ----------
template<int DO_TANH>
__global__ __launch_bounds__(256) void aggregate3(const unsigned char* __restrict__ hs,
    const unsigned short* __restrict__ csr, const int* __restrict__ off,
    const float* __restrict__ dis, const float* __restrict__ bias,
    unsigned* __restrict__ outp, int n) {
    __shared__ unsigned short eidx[ECAP];
    int t = threadIdx.x;
    int node0 = blockIdx.x * 4;
    int b0 = off[node0];
    int top = node0 + 4 < n ? node0 + 4 : n;
    int b4 = off[top];
    int mblk = b4 - b0;
    bool staged = (mblk <= ECAP);
    if (staged)
        for (int i = t; i < mblk; i += 256) eidx[i] = csr[b0 + i];
    __syncthreads();

    int node = node0 + (t >> 6);
    if (node >= n) return;
    int lane = t & 63;
    int half = lane >> 5;
    int fq = lane & 31;
    const unsigned* H = (const unsigned*)hs;   // 32 uints (128 fp8) per row

    int e0 = off[node];
    int e1 = off[node + 1];
    int le0 = e0 - b0;
    int m = e1 - e0;
    float ax = 0.f, ay = 0.f, az = 0.f, aw = 0.f;

    unsigned va[8], vb[8];
    auto sumB = [&](unsigned* v) {
#pragma unroll
        for (int j = 0; j < 8; ++j) {
            ax += __builtin_amdgcn_cvt_f32_fp8(v[j], 0);
            ay += __builtin_amdgcn_cvt_f32_fp8(v[j], 1);
            az += __builtin_amdgcn_cvt_f32_fp8(v[j], 2);
            aw += __builtin_amdgcn_cvt_f32_fp8(v[j], 3);
        }
    };
    auto loadL = [&](int i, unsigned* v) {
        int s[8];
#pragma unroll
        for (int j = 0; j < 8; ++j) s[j] = eidx[le0 + i + half + 2 * j];
#pragma unroll
        for (int j = 0; j < 8; ++j) v[j] = H[(size_t)s[j] * 32 + fq];
    };
    auto loadG = [&](int i, unsigned* v) {
        int s[8];
#pragma unroll
        for (int j = 0; j < 8; ++j) s[j] = csr[e0 + i + half + 2 * j];
#pragma unroll
        for (int j = 0; j < 8; ++j) v[j] = H[(size_t)s[j] * 32 + fq];
    };

    int nfull = m & ~15;
    if (staged) {
        if (nfull) {
            int B = nfull >> 4;
            loadL(0, va);
            int k = 1;
            for (; k + 1 < B; k += 2) {
                loadL(k << 4, vb);       sumB(va);
                loadL((k + 1) << 4, va); sumB(vb);
            }
            if (k < B) { loadL(k << 4, vb); sumB(va); sumB(vb); }
            else       { sumB(va); }
        }
        for (int e = nfull + half; e < m; e += 2) {
            unsigned v = H[(size_t)eidx[le0 + e] * 32 + fq];
            ax += __builtin_amdgcn_cvt_f32_fp8(v, 0);
            ay += __builtin_amdgcn_cvt_f32_fp8(v, 1);
            az += __builtin_amdgcn_cvt_f32_fp8(v, 2);
            aw += __builtin_amdgcn_cvt_f32_fp8(v, 3);
        }
    } else {
        if (nfull) {
            int B = nfull >> 4;
            loadG(0, va);
            int k = 1;
            for (; k + 1 < B; k += 2) {
                loadG(k << 4, vb);       sumB(va);
                loadG((k + 1) << 4, va); sumB(vb);
            }
            if (k < B) { loadG(k << 4, vb); sumB(va); sumB(vb); }
            else       { sumB(va); }
        }
        for (int e = nfull + half; e < m; e += 2) {
            unsigned v = H[(size_t)csr[e0 + e] * 32 + fq];
            ax += __builtin_amdgcn_cvt_f32_fp8(v, 0);
            ay += __builtin_amdgcn_cvt_f32_fp8(v, 1);
            az += __builtin_amdgcn_cvt_f32_fp8(v, 2);
            aw += __builtin_amdgcn_cvt_f32_fp8(v, 3);
        }
    }

    ax += __shfl_xor(ax, 32, 64);
    ay += __shfl_xor(ay, 32, 64);
    az += __shfl_xor(az, 32, 64);
    aw += __shfl_xor(aw, 32, 64);

    unsigned sv = H[(size_t)node * 32 + fq];   // self loop (row pre-scaled)
    ax += __builtin_amdgcn_cvt_f32_fp8(sv, 0);
    ay += __builtin_amdgcn_cvt_f32_fp8(sv, 1);
    az += __builtin_amdgcn_cvt_f32_fp8(sv, 2);
    aw += __builtin_amdgcn_cvt_f32_fp8(sv, 3);

    float dn = dis[node];
    float4 bv = ((const float4*)bias)[fq];
    float ox = fmaf(dn, ax, bv.x);
    float oy = fmaf(dn, ay, bv.y);
    float oz = fmaf(dn, az, bv.z);
    float ow = fmaf(dn, aw, bv.w);
    if (DO_TANH) {
        ox = tanhf(ox); oy = tanhf(oy); oz = tanhf(oz); ow = tanhf(ow);
    }
    if (half == 0) {
        uint2 o;
        o.x = (unsigned)f2bf(ox) | ((unsigned)f2bf(oy) << 16);
        o.y = (unsigned)f2bf(oz) | ((unsigned)f2bf(ow) << 16);
        *(uint2*)(outp + (size_t)node * 64 + fq * 2) = o;   // bf16 row (64 uints)
    }
}

// ---- fused pool + head: 256 threads (4 waves) per graph, bf16 act ---------
__global__ __launch_bounds__(256) void pool_head(const unsigned* __restrict__ actb,
    const int* __restrict__ batch, const float* __restrict__ Wout,
    const float* __restrict__ bout, float* __restrict__ out, int n, int C) {
    __shared__ float psum[4][128];
    __shared__ float l[16];
    __shared__ float stats[2];
    int g = blockIdx.x;
    int t = threadIdx.x;
    int w = t >> 6;
    int lane = t & 63;
    int lo = 0, hi = n;
    while (lo < hi) { int mid = (lo + hi) >> 1; if (batch[mid] < g) lo = mid + 1; else hi = mid; }
    int lo1 = lo, hi1 = n;
    while (lo1 < hi1) { int mid = (lo1 + hi1) >> 1; if (batch[mid] < g + 1) lo1 = mid + 1; else hi1 = mid; }
    float ax = 0.f, ay = 0.f;
    for (int i = lo + w; i < lo1; i += 4) {
        unsigned v = actb[(size_t)i * 64 + lane];     // 2 bf16 feats
        ax += bf_lo(v);
        ay += bf_hi(v);
    }
    psum[w][2 * lane]     = ax;
    psum[w][2 * lane + 1] = ay;
    __syncthreads();
    if (w == 0) {
        int cnt = lo1 - lo;
        float inv = 1.0f / (float)(cnt > 0 ? cnt : 1);
        float sx = (psum[0][2 * lane] + psum[1][2 * lane])
                 + (psum[2][2 * lane] + psum[3][2 * lane]);
        float sy = (psum[0][2 * lane + 1] + psum[1][2 * lane + 1])
                 + (psum[2][2 * lane + 1] + psum[3][2 * lane + 1]);
        psum[0][2 * lane]     = sx * inv;   // reuse psum[0] as pooled
        psum[0][2 * lane + 1] = sy * inv;
    }
    __syncthreads();
    if (t < C) {
        float acc = bout[t];
        for (int f = 0; f < 128; ++f)
            acc = fmaf(psum[0][f], Wout[(size_t)f * C + t], acc);
        l[t] = acc;
    }
    __syncthreads();
    if (t == 0) {
        float m = -1e30f;
        for (int c = 0; c < C; ++c) m = fmaxf(m, l[c]);
        float s = 0.f;
        for (int c = 0; c < C; ++c) s += expf(l[c] - m);
        stats[0] = m;
        stats[1] = logf(s);
    }
    __syncthreads();
    if (t < C) out[(size_t)g * C + t] = l[t] - stats[0] - stats[1];
}

// ---------------------------------------------------------------------------
extern "C" void kernel_launch(void* const* d_in, const int* in_sizes, int n_in,
                              void* d_out, int out_size, void* d_ws, size_t ws_size,
                              hipStream_t stream) {
    const float* x     = (const float*)d_in[0];
    const int*   edge  = (const int*)d_in[1];
    const int*   batch = (const int*)d_in[2];
    const float* W0 = (const float*)d_in[3];
    const float* b0 = (const float*)d_in[4];
    const float* W1 = (const float*)d_in[5];
    const float* b1 = (const float*)d_in[6];
    const float* W2 = (const float*)d_in[7];
    const float* b2 = (const float*)d_in[8];
    const float* Wout = (const float*)d_in[9];
    const float* bout = (const float*)d_in[10];
    float* out = (float*)d_out;

    const int N = in_sizes[0] / 128;   // 50000 (< 65536 required for packing)
    const int E = in_sizes[1] / 2;     // 1600000
    const int C = in_sizes[10];        // 10
    const int G = out_size / C;        // 512

    const int* src = edge;
    const int* dst = edge + E;

    const int NBLK = (E + BLK_EDGES - 1) / BLK_EDGES;  // 391
    const int NB   = (N + 511) / 512;                  // 98 buckets
    const int NBQ  = NB * NBLK;                        // 38318 scan entries
    const int PREPB = (3 * 16384) / 256;               // 192 weight-prep blocks

    char* p = (char*)d_ws;
    auto alloc = [&](size_t bytes) -> void* {
        void* r = (void*)p;
        p += (bytes + 255) & ~(size_t)255;
        return r;
    };
    unsigned char* hs = (unsigned char*)alloc((size_t)N * 128);   // fp8 table
    unsigned* actb = (unsigned*)alloc((size_t)N * 128 * 2);       // bf16 act
    float* dis    = (float*)alloc((size_t)N * 4);
    int*   off    = (int*)alloc((size_t)(N + 1) * 4);
    int*   P      = (int*)alloc((size_t)(NBQ + 1) * 4);
    int*   bsum   = (int*)alloc(256 * 4);
    int*   boff   = (int*)alloc(256 * 4);
    unsigned* packed = (unsigned*)alloc((size_t)E * 4);
    unsigned short* csr16 = (unsigned short*)alloc((size_t)E * 2);
    unsigned short* wt0 = (unsigned short*)alloc(128 * 128 * 2);
    unsigned short* wt1 = (unsigned short*)alloc(128 * 128 * 2);
    unsigned short* wt2 = (unsigned short*)alloc(128 * 128 * 2);

    const int sb = (NBQ + 255) / 256;   // 150 (<=256 required by scan_top)

    // CSR build + weight prep (fused into the first launch's extra blocks)
    blk_hist_prep<<<NBLK + PREPB, 256, 0, stream>>>(dst, P, E, NBLK, NB,
                                                    W0, W1, W2, wt0, wt1, wt2);
    scan_block<<<sb, 256, 0, stream>>>(P, P, bsum, NBQ);
    scan_top<<<1, 256, 0, stream>>>(bsum, boff, sb);
    scatter_packed<<<NBLK, 256, 0, stream>>>(src, dst, P, boff, packed, E, NBLK, NB);
    bucket_build<<<NB, 256, 0, stream>>>(packed, P, boff, off, dis, csr16, E, NBLK, N, NB);

    const int gb = (N + 63) / 64;    // 782 blocks of 128 threads
    const int ab = (N + 3) / 4;

    gemm_mfma<1><<<gb, 128, 0, stream>>>(x,    wt0, dis, hs, N);
    aggregate3<1><<<ab, 256, 0, stream>>>(hs, csr16, off, dis, b0, actb, N);
    gemm_mfma<0><<<gb, 128, 0, stream>>>(actb, wt1, dis, hs, N);
    aggregate3<1><<<ab, 256, 0, stream>>>(hs, csr16, off, dis, b1, actb, N);
    gemm_mfma<0><<<gb, 128, 0, stream>>>(actb, wt2, dis, hs, N);
    aggregate3<0><<<ab, 256, 0, stream>>>(hs, csr16, off, dis, b2, actb, N);

    pool_head<<<G, 256, 0, stream>>>(actb, batch, Wout, bout, out, N, C);
}

// Round 15
// 320.256 us; speedup vs baseline: 1.6964x; 1.0357x over previous
//
#include <hip/hip_runtime.h>
#include <math.h>

// ---------------------------------------------------------------------------
// GCN: 3x (MFMA GEMM(+dis scale, fp8 table out) -> pull-aggregate -> tanh)
//      -> fused pool+head
// R15: aggregate tail eliminated — batches rounded up to ceil(m/16) with
//      per-lane masking (fp8 0x00 == +0.0, masked lanes add nothing). The
//      old serial 2-edge/iter remainder loop (~4 latency-bound iters at mean
//      degree 32) becomes one more pipelined batch. Rest identical to R14.
// ---------------------------------------------------------------------------

#define BLK_EDGES 4096
#define MAXB 128          // max dst-buckets for CSR build (N<=65536)
#define ECAP 2048         // LDS edge-index capacity per aggregate block
#define WS_STRIDE 136     // LDS row stride for W^T (elements; 272B, 16B-aligned)

typedef __attribute__((ext_vector_type(8))) short bf16x8;
typedef __attribute__((ext_vector_type(4))) float f32x4;

static __device__ inline unsigned short f2bf(float f) {
    unsigned u = __float_as_uint(f);
    unsigned r = (u + 0x7FFFu + ((u >> 16) & 1u)) >> 16;   // RNE
    return (unsigned short)r;
}
static __device__ inline float bf_lo(unsigned u) { return __uint_as_float(u << 16); }
static __device__ inline float bf_hi(unsigned u) { return __uint_as_float(u & 0xFFFF0000u); }
static __device__ inline unsigned char f2fp8(float v) {
    v = fminf(fmaxf(v, -240.f), 240.f);                    // avoid e4m3 NaN
    int u = __builtin_amdgcn_cvt_pk_fp8_f32(v, v, 0, false);
    return (unsigned char)(u & 0xFF);
}

// ---- bucket histogram (blocks < NBLK) + weight transpose (blocks >= NBLK) -
__global__ __launch_bounds__(256) void blk_hist_prep(const int* __restrict__ dst,
        int* __restrict__ histT, int E, int NBLK, int NB,
        const float* __restrict__ W0, const float* __restrict__ W1,
        const float* __restrict__ W2, unsigned short* __restrict__ wt0,
        unsigned short* __restrict__ wt1, unsigned short* __restrict__ wt2) {
    __shared__ int h[MAXB];
    int blk = blockIdx.x, t = threadIdx.x;
    if (blk >= NBLK) {
        int i = (blk - NBLK) * 256 + t;       // covers 3*16384 exactly (192 blocks)
        int w = i >> 14, j = i & 16383;
        int k = j >> 7, n2 = j & 127;
        const float* Wp = (w == 0) ? W0 : (w == 1) ? W1 : W2;
        unsigned short* Wt = (w == 0) ? wt0 : (w == 1) ? wt1 : wt2;
        Wt[n2 * 128 + k] = f2bf(Wp[k * 128 + n2]);
        return;
    }
    for (int i = t; i < NB; i += 256) h[i] = 0;
    __syncthreads();
    int lo = blk * BLK_EDGES;
    int hi = min(E, lo + BLK_EDGES);
    for (int i = lo + t; i < hi; i += 256)
        atomicAdd(&h[dst[i] >> 9], 1);
    __syncthreads();
    for (int i = t; i < NB; i += 256) histT[i * NBLK + blk] = h[i];
}

// ---- 2-kernel scan (per-chunk exclusive + chunk offsets; consumers fold) --
__global__ void scan_block(const int* __restrict__ cnt, int* __restrict__ off,
                           int* __restrict__ bsum, int n) {
    __shared__ int lds[256];
    int t = threadIdx.x;
    int i = blockIdx.x * 256 + t;
    int v = (i < n) ? cnt[i] : 0;
    lds[t] = v;
    __syncthreads();
    for (int d = 1; d < 256; d <<= 1) {
        int add = (t >= d) ? lds[t - d] : 0;
        __syncthreads();
        lds[t] += add;
        __syncthreads();
    }
    if (i < n) off[i] = lds[t] - v;      // exclusive within 256-chunk
    if (t == 255) bsum[blockIdx.x] = lds[255];
}

__global__ void scan_top(const int* __restrict__ bsum, int* __restrict__ boff,
                         int nblocks) {
    __shared__ int lds[256];
    int t = threadIdx.x;
    int v = (t < nblocks) ? bsum[t] : 0;
    lds[t] = v;
    __syncthreads();
    for (int d = 1; d < 256; d <<= 1) {
        int add = (t >= d) ? lds[t - d] : 0;
        __syncthreads();
        lds[t] += add;
        __syncthreads();
    }
    if (t < nblocks) boff[t] = lds[t] - v;   // exclusive chunk offsets
}

// ---- scatter packed edges into private (block,bucket) runs ----------------
__global__ __launch_bounds__(256) void scatter_packed(const int* __restrict__ src,
        const int* __restrict__ dst, const int* __restrict__ P,
        const int* __restrict__ boff, unsigned* __restrict__ packed,
        int E, int NBLK, int NB) {
    __shared__ int cur[MAXB];
    int blk = blockIdx.x, t = threadIdx.x;
    for (int i = t; i < NB; i += 256) {
        int idx = i * NBLK + blk;
        cur[i] = P[idx] + boff[idx >> 8];
    }
    __syncthreads();
    int lo = blk * BLK_EDGES;
    int hi = min(E, lo + BLK_EDGES);
    for (int i = lo + t; i < hi; i += 256) {
        int d = dst[i];
        int pos = atomicAdd(&cur[d >> 9], 1);   // LDS atomic, block-local
        packed[pos] = ((unsigned)d << 16) | (unsigned)src[i];
    }
}

// ---- per-bucket: node counts, local scan -> off/dis, fill ushort CSR ------
__global__ __launch_bounds__(256) void bucket_build(const unsigned* __restrict__ packed,
        const int* __restrict__ P, const int* __restrict__ boff, int* __restrict__ off,
        float* __restrict__ dis, unsigned short* __restrict__ csr16,
        int E, int NBLK, int N, int NB) {
    __shared__ int cnt[512];
    __shared__ int loc[512];
    __shared__ int ps[256];
    int b = blockIdx.x, t = threadIdx.x;
    int i0 = b * NBLK, i1 = (b + 1) * NBLK;
    int start = P[i0] + boff[i0 >> 8];
    int end   = (b == NB - 1) ? E : (P[i1] + boff[i1 >> 8]);
    cnt[t] = 0; cnt[t + 256] = 0;
    __syncthreads();
    for (int i = start + t; i < end; i += 256)
        atomicAdd(&cnt[(packed[i] >> 16) & 511], 1);
    __syncthreads();
    int c0 = cnt[2 * t], c1 = cnt[2 * t + 1];
    ps[t] = c0 + c1;
    __syncthreads();
    for (int d = 1; d < 256; d <<= 1) {
        int add = (t >= d) ? ps[t - d] : 0;
        __syncthreads();
        ps[t] += add;
        __syncthreads();
    }
    int pexcl = ps[t] - (c0 + c1);
    loc[2 * t]     = start + pexcl;
    loc[2 * t + 1] = start + pexcl + c0;
    __syncthreads();
    int node0 = b * 512;
    for (int l = t; l < 512; l += 256) {
        int node = node0 + l;
        if (node < N) {
            off[node] = loc[l];
            dis[node] = rsqrtf((float)cnt[l] + 1.0f);
        }
    }
    if (b == NB - 1 && t == 0) off[N] = E;
    __syncthreads();
    for (int i = start + t; i < end; i += 256) {
        unsigned p = packed[i];
        int l = (p >> 16) & 511;
        int pos = atomicAdd(&loc[l], 1);
        csr16[pos] = (unsigned short)(p & 0xFFFFu);
    }
}

// ---- MFMA GEMM: Hs8[r] = fp8( dis[r] * (A[r] @ W) ) -----------------------
template<int IN_F32>
__global__ __launch_bounds__(128) void gemm_mfma(const void* __restrict__ Av,
        const unsigned short* __restrict__ Wt, const float* __restrict__ dis,
        unsigned char* __restrict__ Hs8, int n) {
    __shared__ unsigned short Ws[128 * WS_STRIDE];   // 34.8 KB
    int t = threadIdx.x;
    for (int i = t; i < 128 * 16; i += 128) {
        int r = i >> 4, j = i & 15;
        uint4 u = ((const uint4*)(Wt + r * 128))[j];
        *(uint4*)&Ws[r * WS_STRIDE + j * 8] = u;
    }
    __syncthreads();

    int wave = t >> 6, lane = t & 63;
    int quad = lane >> 4, l16 = lane & 15;
    int row0 = blockIdx.x * 64 + wave * 32;

    int ra0 = row0 + l16;      if (ra0 >= n) ra0 = n - 1;
    int ra1 = row0 + 16 + l16; if (ra1 >= n) ra1 = n - 1;

    f32x4 acc[2][8];
    const f32x4 z = {0.f, 0.f, 0.f, 0.f};
#pragma unroll
    for (int mi = 0; mi < 2; ++mi)
#pragma unroll
        for (int ni = 0; ni < 8; ++ni) acc[mi][ni] = z;

#pragma unroll
    for (int ks = 0; ks < 4; ++ks) {
        int kof = ks * 32 + quad * 8;
        bf16x8 a0, a1;
        if (IN_F32) {
            const float* A0 = (const float*)Av + (size_t)ra0 * 128 + kof;
            const float* A1 = (const float*)Av + (size_t)ra1 * 128 + kof;
            float4 p0 = ((const float4*)A0)[0], p1 = ((const float4*)A0)[1];
            float4 q0 = ((const float4*)A1)[0], q1 = ((const float4*)A1)[1];
            a0[0] = (short)f2bf(p0.x); a0[1] = (short)f2bf(p0.y);
            a0[2] = (short)f2bf(p0.z); a0[3] = (short)f2bf(p0.w);
            a0[4] = (short)f2bf(p1.x); a0[5] = (short)f2bf(p1.y);
            a0[6] = (short)f2bf(p1.z); a0[7] = (short)f2bf(p1.w);
            a1[0] = (short)f2bf(q0.x); a1[1] = (short)f2bf(q0.y);
            a1[2] = (short)f2bf(q0.z); a1[3] = (short)f2bf(q0.w);
            a1[4] = (short)f2bf(q1.x); a1[5] = (short)f2bf(q1.y);
            a1[6] = (short)f2bf(q1.z); a1[7] = (short)f2bf(q1.w);
        } else {
            a0 = *(const bf16x8*)((const unsigned short*)Av + (size_t)ra0 * 128 + kof);
            a1 = *(const bf16x8*)((const unsigned short*)Av + (size_t)ra1 * 128 + kof);
        }
        bf16x8 b[8];
#pragma unroll
        for (int ni = 0; ni < 8; ++ni)
            b[ni] = *(const bf16x8*)&Ws[(ni * 16 + l16) * WS_STRIDE + kof];
#pragma unroll
        for (int ni = 0; ni < 8; ++ni) {
            acc[0][ni] = __builtin_amdgcn_mfma_f32_16x16x32_bf16(a0, b[ni], acc[0][ni], 0, 0, 0);
            acc[1][ni] = __builtin_amdgcn_mfma_f32_16x16x32_bf16(a1, b[ni], acc[1][ni], 0, 0, 0);
        }
    }
#pragma unroll
    for (int mi = 0; mi < 2; ++mi) {
        int rb = row0 + mi * 16 + quad * 4;
#pragma unroll
        for (int reg = 0; reg < 4; ++reg) {
            int r = rb + reg;
            if (r < n) {
                float dv = dis[r];
#pragma unroll
                for (int ni = 0; ni < 8; ++ni)
                    Hs8[(size_t)r * 128 + ni * 16 + l16] = f2fp8(acc[mi][ni][reg] * dv);
            }
        }
    }
}

// ---- pull aggregation over fp8 table: masked pipelined batches ------------
// ceil(m/16) batches of 16 edges (8/half-wave stream), out-of-range lanes
// masked to 0 (fp8 zero). No serial tail loop.
template<int DO_TANH>
__global__ __launch_bounds__(256) void aggregate3(const unsigned char* __restrict__ hs,
    const unsigned short* __restrict__ csr, const int* __restrict__ off,
    const float* __restrict__ dis, const float* __restrict__ bias,
    unsigned* __restrict__ outp, int n) {
    __shared__ unsigned short eidx[ECAP];
    int t = threadIdx.x;
    int node0 = blockIdx.x * 4;
    int b0 = off[node0];
    int top = node0 + 4 < n ? node0 + 4 : n;
    int b4 = off[top];
    int mblk = b4 - b0;
    bool staged = (mblk <= ECAP);
    if (staged)
        for (int i = t; i < mblk; i += 256) eidx[i] = csr[b0 + i];
    __syncthreads();

    int node = node0 + (t >> 6);
    if (node >= n) return;
    int lane = t & 63;
    int half = lane >> 5;
    int fq = lane & 31;
    const unsigned* H = (const unsigned*)hs;   // 32 uints (128 fp8) per row

    int e0 = off[node];
    int e1 = off[node + 1];
    int le0 = e0 - b0;
    int m = e1 - e0;
    float ax = 0.f, ay = 0.f, az = 0.f, aw = 0.f;

    unsigned va[8], vb[8];
    auto sumB = [&](unsigned* v) {
#pragma unroll
        for (int j = 0; j < 8; ++j) {
            ax += __builtin_amdgcn_cvt_f32_fp8(v[j], 0);
            ay += __builtin_amdgcn_cvt_f32_fp8(v[j], 1);
            az += __builtin_amdgcn_cvt_f32_fp8(v[j], 2);
            aw += __builtin_amdgcn_cvt_f32_fp8(v[j], 3);
        }
    };
    // masked batch loads: edge e = i + half + 2j; e >= m contributes 0
    auto loadL = [&](int i, unsigned* v) {
#pragma unroll
        for (int j = 0; j < 8; ++j) {
            int e = i + half + 2 * j;
            unsigned val = 0u;
            if (e < m) val = H[(size_t)eidx[le0 + e] * 32 + fq];
            v[j] = val;
        }
    };
    auto loadG = [&](int i, unsigned* v) {
#pragma unroll
        for (int j = 0; j < 8; ++j) {
            int e = i + half + 2 * j;
            unsigned val = 0u;
            if (e < m) val = H[(size_t)csr[e0 + e] * 32 + fq];
            v[j] = val;
        }
    };

    int B = (m + 15) >> 4;          // masked batches, no tail
    if (B) {
        if (staged) {
            loadL(0, va);
            int k = 1;
            for (; k + 1 < B; k += 2) {
                loadL(k << 4, vb);       sumB(va);
                loadL((k + 1) << 4, va); sumB(vb);
            }
            if (k < B) { loadL(k << 4, vb); sumB(va); sumB(vb); }
            else       { sumB(va); }
        } else {
            loadG(0, va);
            int k = 1;
            for (; k + 1 < B; k += 2) {
                loadG(k << 4, vb);       sumB(va);
                loadG((k + 1) << 4, va); sumB(vb);
            }
            if (k < B) { loadG(k << 4, vb); sumB(va); sumB(vb); }
            else       { sumB(va); }
        }
    }

    ax += __shfl_xor(ax, 32, 64);
    ay += __shfl_xor(ay, 32, 64);
    az += __shfl_xor(az, 32, 64);
    aw += __shfl_xor(aw, 32, 64);

    unsigned sv = H[(size_t)node * 32 + fq];   // self loop (row pre-scaled)
    ax += __builtin_amdgcn_cvt_f32_fp8(sv, 0);
    ay += __builtin_amdgcn_cvt_f32_fp8(sv, 1);
    az += __builtin_amdgcn_cvt_f32_fp8(sv, 2);
    aw += __builtin_amdgcn_cvt_f32_fp8(sv, 3);

    float dn = dis[node];
    float4 bv = ((const float4*)bias)[fq];
    float ox = fmaf(dn, ax, bv.x);
    float oy = fmaf(dn, ay, bv.y);
    float oz = fmaf(dn, az, bv.z);
    float ow = fmaf(dn, aw, bv.w);
    if (DO_TANH) {
        ox = tanhf(ox); oy = tanhf(oy); oz = tanhf(oz); ow = tanhf(ow);
    }
    if (half == 0) {
        uint2 o;
        o.x = (unsigned)f2bf(ox) | ((unsigned)f2bf(oy) << 16);
        o.y = (unsigned)f2bf(oz) | ((unsigned)f2bf(ow) << 16);
        *(uint2*)(outp + (size_t)node * 64 + fq * 2) = o;   // bf16 row (64 uints)
    }
}

// ---- fused pool + head: 256 threads (4 waves) per graph, bf16 act ---------
__global__ __launch_bounds__(256) void pool_head(const unsigned* __restrict__ actb,
    const int* __restrict__ batch, const float* __restrict__ Wout,
    const float* __restrict__ bout, float* __restrict__ out, int n, int C) {
    __shared__ float psum[4][128];
    __shared__ float l[16];
    __shared__ float stats[2];
    int g = blockIdx.x;
    int t = threadIdx.x;
    int w = t >> 6;
    int lane = t & 63;
    int lo = 0, hi = n;
    while (lo < hi) { int mid = (lo + hi) >> 1; if (batch[mid] < g) lo = mid + 1; else hi = mid; }
    int lo1 = lo, hi1 = n;
    while (lo1 < hi1) { int mid = (lo1 + hi1) >> 1; if (batch[mid] < g + 1) lo1 = mid + 1; else hi1 = mid; }
    float ax = 0.f, ay = 0.f;
    for (int i = lo + w; i < lo1; i += 4) {
        unsigned v = actb[(size_t)i * 64 + lane];     // 2 bf16 feats
        ax += bf_lo(v);
        ay += bf_hi(v);
    }
    psum[w][2 * lane]     = ax;
    psum[w][2 * lane + 1] = ay;
    __syncthreads();
    if (w == 0) {
        int cnt = lo1 - lo;
        float inv = 1.0f / (float)(cnt > 0 ? cnt : 1);
        float sx = (psum[0][2 * lane] + psum[1][2 * lane])
                 + (psum[2][2 * lane] + psum[3][2 * lane]);
        float sy = (psum[0][2 * lane + 1] + psum[1][2 * lane + 1])
                 + (psum[2][2 * lane + 1] + psum[3][2 * lane + 1]);
        psum[0][2 * lane]     = sx * inv;   // reuse psum[0] as pooled
        psum[0][2 * lane + 1] = sy * inv;
    }
    __syncthreads();
    if (t < C) {
        float acc = bout[t];
        for (int f = 0; f < 128; ++f)
            acc = fmaf(psum[0][f], Wout[(size_t)f * C + t], acc);
        l[t] = acc;
    }
    __syncthreads();
    if (t == 0) {
        float m = -1e30f;
        for (int c = 0; c < C; ++c) m = fmaxf(m, l[c]);
        float s = 0.f;
        for (int c = 0; c < C; ++c) s += expf(l[c] - m);
        stats[0] = m;
        stats[1] = logf(s);
    }
    __syncthreads();
    if (t < C) out[(size_t)g * C + t] = l[t] - stats[0] - stats[1];
}

// ---------------------------------------------------------------------------
extern "C" void kernel_launch(void* const* d_in, const int* in_sizes, int n_in,
                              void* d_out, int out_size, void* d_ws, size_t ws_size,
                              hipStream_t stream) {
    const float* x     = (const float*)d_in[0];
    const int*   edge  = (const int*)d_in[1];
    const int*   batch = (const int*)d_in[2];
    const float* W0 = (const float*)d_in[3];
    const float* b0 = (const float*)d_in[4];
    const float* W1 = (const float*)d_in[5];
    const float* b1 = (const float*)d_in[6];
    const float* W2 = (const float*)d_in[7];
    const float* b2 = (const float*)d_in[8];
    const float* Wout = (const float*)d_in[9];
    const float* bout = (const float*)d_in[10];
    float* out = (float*)d_out;

    const int N = in_sizes[0] / 128;   // 50000 (< 65536 required for packing)
    const int E = in_sizes[1] / 2;     // 1600000
    const int C = in_sizes[10];        // 10
    const int G = out_size / C;        // 512

    const int* src = edge;
    const int* dst = edge + E;

    const int NBLK = (E + BLK_EDGES - 1) / BLK_EDGES;  // 391
    const int NB   = (N + 511) / 512;                  // 98 buckets
    const int NBQ  = NB * NBLK;                        // 38318 scan entries
    const int PREPB = (3 * 16384) / 256;               // 192 weight-prep blocks

    char* p = (char*)d_ws;
    auto alloc = [&](size_t bytes) -> void* {
        void* r = (void*)p;
        p += (bytes + 255) & ~(size_t)255;
        return r;
    };
    unsigned char* hs = (unsigned char*)alloc((size_t)N * 128);   // fp8 table
    unsigned* actb = (unsigned*)alloc((size_t)N * 128 * 2);       // bf16 act
    float* dis    = (float*)alloc((size_t)N * 4);
    int*   off    = (int*)alloc((size_t)(N + 1) * 4);
    int*   P      = (int*)alloc((size_t)(NBQ + 1) * 4);
    int*   bsum   = (int*)alloc(256 * 4);
    int*   boff   = (int*)alloc(256 * 4);
    unsigned* packed = (unsigned*)alloc((size_t)E * 4);
    unsigned short* csr16 = (unsigned short*)alloc((size_t)E * 2);
    unsigned short* wt0 = (unsigned short*)alloc(128 * 128 * 2);
    unsigned short* wt1 = (unsigned short*)alloc(128 * 128 * 2);
    unsigned short* wt2 = (unsigned short*)alloc(128 * 128 * 2);

    const int sb = (NBQ + 255) / 256;   // 150 (<=256 required by scan_top)

    // CSR build + weight prep (fused into the first launch's extra blocks)
    blk_hist_prep<<<NBLK + PREPB, 256, 0, stream>>>(dst, P, E, NBLK, NB,
                                                    W0, W1, W2, wt0, wt1, wt2);
    scan_block<<<sb, 256, 0, stream>>>(P, P, bsum, NBQ);
    scan_top<<<1, 256, 0, stream>>>(bsum, boff, sb);
    scatter_packed<<<NBLK, 256, 0, stream>>>(src, dst, P, boff, packed, E, NBLK, NB);
    bucket_build<<<NB, 256, 0, stream>>>(packed, P, boff, off, dis, csr16, E, NBLK, N, NB);

    const int gb = (N + 63) / 64;    // 782 blocks of 128 threads
    const int ab = (N + 3) / 4;

    gemm_mfma<1><<<gb, 128, 0, stream>>>(x,    wt0, dis, hs, N);
    aggregate3<1><<<ab, 256, 0, stream>>>(hs, csr16, off, dis, b0, actb, N);
    gemm_mfma<0><<<gb, 128, 0, stream>>>(actb, wt1, dis, hs, N);
    aggregate3<1><<<ab, 256, 0, stream>>>(hs, csr16, off, dis, b1, actb, N);
    gemm_mfma<0><<<gb, 128, 0, stream>>>(actb, wt2, dis, hs, N);
    aggregate3<0><<<ab, 256, 0, stream>>>(hs, csr16, off, dis, b2, actb, N);

    pool_head<<<G, 256, 0, stream>>>(actb, batch, Wout, bout, out, N, C);
}